// Round 1
// baseline (1232.079 us; speedup 1.0000x reference)
//
#include <hip/hip_runtime.h>
#include <cmath>

#define H    512
#define H2   1024
#define H3   1536
#define V    50000
#define SEQ  400
#define BATCH 64
#define EXT  (V + SEQ)   // 50400

// ---------------------------------------------------------------------------
// K1: single-step GRU.  grid=128 blocks x 256 thr.  wave -> column j (512 of
// them), lane -> batch b.  x/h0 staged transposed in LDS (pad 68 keeps float4
// rows 16B-aligned and bank-spread); W rows read wave-uniform (broadcast).
// ---------------------------------------------------------------------------
__global__ __launch_bounds__(256) void k1_gru(
    const float* __restrict__ x, const float* __restrict__ h0,
    const float* __restrict__ W_ih, const float* __restrict__ W_hh,
    const float* __restrict__ b_ih, const float* __restrict__ b_hh,
    float* __restrict__ h_out)
{
    __shared__ float xs[64][68];
    __shared__ float hs[64][68];
    const int tid  = threadIdx.x;
    const int j    = blockIdx.x * 4 + (tid >> 6);
    const int lane = tid & 63;

    float a_ir = 0.f, a_iz = 0.f, a_in = 0.f, a_hr = 0.f, a_hz = 0.f, a_hn = 0.f;
    const float* wr_i = W_ih + (size_t)j * H;
    const float* wz_i = W_ih + (size_t)(H + j) * H;
    const float* wn_i = W_ih + (size_t)(2 * H + j) * H;
    const float* wr_h = W_hh + (size_t)j * H;
    const float* wz_h = W_hh + (size_t)(H + j) * H;
    const float* wn_h = W_hh + (size_t)(2 * H + j) * H;

    for (int kc = 0; kc < H; kc += 64) {
        __syncthreads();
        #pragma unroll
        for (int e = tid; e < 64 * 64; e += 256) {
            int bb = e >> 6, kk = e & 63;
            xs[bb][kk] = x[bb * H + kc + kk];
            hs[bb][kk] = h0[bb * H + kc + kk];
        }
        __syncthreads();
        #pragma unroll
        for (int kk = 0; kk < 64; kk += 4) {
            float4 xv = *(const float4*)&xs[lane][kk];
            float4 hv = *(const float4*)&hs[lane][kk];
            float4 w;
            w = *(const float4*)&wr_i[kc + kk];
            a_ir += w.x * xv.x + w.y * xv.y + w.z * xv.z + w.w * xv.w;
            w = *(const float4*)&wz_i[kc + kk];
            a_iz += w.x * xv.x + w.y * xv.y + w.z * xv.z + w.w * xv.w;
            w = *(const float4*)&wn_i[kc + kk];
            a_in += w.x * xv.x + w.y * xv.y + w.z * xv.z + w.w * xv.w;
            w = *(const float4*)&wr_h[kc + kk];
            a_hr += w.x * hv.x + w.y * hv.y + w.z * hv.z + w.w * hv.w;
            w = *(const float4*)&wz_h[kc + kk];
            a_hz += w.x * hv.x + w.y * hv.y + w.z * hv.z + w.w * hv.w;
            w = *(const float4*)&wn_h[kc + kk];
            a_hn += w.x * hv.x + w.y * hv.y + w.z * hv.z + w.w * hv.w;
        }
    }
    // PyTorch gate order r, z, n;  n-gate bias of gh multiplied by r.
    float r = 1.f / (1.f + expf(-(a_ir + b_ih[j] + a_hr + b_hh[j])));
    float z = 1.f / (1.f + expf(-(a_iz + b_ih[H + j] + a_hz + b_hh[H + j])));
    float n = tanhf(a_in + b_ih[2 * H + j] + r * (a_hn + b_hh[2 * H + j]));
    float h0v = h0[lane * H + j];
    h_out[lane * H + j] = (1.f - z) * n + z * h0v;
}

// ---------------------------------------------------------------------------
// K2: x2 = h @ Ws + b_attn, plus p partial  pd[b] = h.pWs + x.pWx + pWx_b.
// grid=64 (b), block=512 (k).  Ws rows coalesced across lanes.
// ---------------------------------------------------------------------------
__global__ __launch_bounds__(512) void k2_post(
    const float* __restrict__ h, const float* __restrict__ Ws,
    const float* __restrict__ b_attn, const float* __restrict__ x,
    const float* __restrict__ pWs, const float* __restrict__ pWx,
    const float* __restrict__ pWx_b,
    float* __restrict__ x2, float* __restrict__ pd)
{
    const int b = blockIdx.x;
    const int k = threadIdx.x;
    __shared__ float hsh[H];
    __shared__ float rbuf[8];
    hsh[k] = h[b * H + k];
    __syncthreads();
    float acc = 0.f;
    #pragma unroll 8
    for (int m = 0; m < H; ++m) acc += hsh[m] * Ws[(size_t)m * H + k];
    x2[b * H + k] = acc + b_attn[k];

    float pp = hsh[k] * pWs[k] + x[b * H + k] * pWx[k];
    #pragma unroll
    for (int off = 32; off > 0; off >>= 1) pp += __shfl_down(pp, off, 64);
    if ((k & 63) == 0) rbuf[k >> 6] = pp;
    __syncthreads();
    if (k == 0) {
        float t = pWx_b[0];
        #pragma unroll
        for (int w = 0; w < 8; ++w) t += rbuf[w];
        pd[b] = t;
    }
}

// ---------------------------------------------------------------------------
// K3: the big one.  score[s,b] = sum_n tanh((enc[s,b,:]@Wh)[n] + x2[b,n]) v[n]
// GEMM M=25600 (rows of enc), N=512, K=512 with fused tanh.v reduction.
// grid = (400 s, 4 n-chunks of 128); block 256; per-thread 8m x 4n register
// tile; A 64x64 + B 64x128 fp32 LDS tiles (~50KB -> 3 blk/CU).
// Writes 4 n-chunk partial scores (deterministic, no atomics).
// ---------------------------------------------------------------------------
__global__ __launch_bounds__(256) void k3_scores(
    const float* __restrict__ enc, const float* __restrict__ Wh,
    const float* __restrict__ x2, const float* __restrict__ v,
    float* __restrict__ part)
{
    __shared__ float As[64][65];
    __shared__ float Bs[64][132];   // row stride 132 floats = 528B, 16B-aligned
    const int s   = blockIdx.x;
    const int nc  = blockIdx.y;
    const int tid = threadIdx.x;
    const int tn  = tid & 31;   // n group: 4 cols each
    const int tm  = tid >> 5;   // m group: 8 rows each
    float acc[8][4];
    #pragma unroll
    for (int i = 0; i < 8; ++i)
        #pragma unroll
        for (int jj = 0; jj < 4; ++jj) acc[i][jj] = 0.f;

    const float* A = enc + (size_t)s * 64 * H;
    for (int kc = 0; kc < H; kc += 64) {
        __syncthreads();
        #pragma unroll
        for (int e = tid; e < 4096; e += 256) {
            int m = e >> 6, kk = e & 63;
            As[m][kk] = A[m * H + kc + kk];
        }
        #pragma unroll
        for (int e = tid; e < 8192; e += 256) {
            int kk = e >> 7, nn = e & 127;
            Bs[kk][nn] = Wh[(size_t)(kc + kk) * H + nc * 128 + nn];
        }
        __syncthreads();
        #pragma unroll 4
        for (int kk = 0; kk < 64; ++kk) {
            float4 bv = *(const float4*)&Bs[kk][tn * 4];
            #pragma unroll
            for (int i = 0; i < 8; ++i) {
                float av = As[tm * 8 + i][kk];   // half-wave broadcast read
                acc[i][0] += av * bv.x;
                acc[i][1] += av * bv.y;
                acc[i][2] += av * bv.z;
                acc[i][3] += av * bv.w;
            }
        }
    }
    // fused epilogue: tanh(+x2) * v, reduce over this thread's 4 n
    float ps[8];
    const int nbase = nc * 128 + tn * 4;
    #pragma unroll
    for (int i = 0; i < 8; ++i) {
        const int b = tm * 8 + i;  // row within tile == batch index
        float t0 = tanhf(acc[i][0] + x2[b * H + nbase + 0]) * v[nbase + 0];
        float t1 = tanhf(acc[i][1] + x2[b * H + nbase + 1]) * v[nbase + 1];
        float t2 = tanhf(acc[i][2] + x2[b * H + nbase + 2]) * v[nbase + 2];
        float t3 = tanhf(acc[i][3] + x2[b * H + nbase + 3]) * v[nbase + 3];
        ps[i] = t0 + t1 + t2 + t3;
    }
    __syncthreads();
    float* red = &As[0][0];          // reuse As as red[64][33]
    #pragma unroll
    for (int i = 0; i < 8; ++i) red[(tm * 8 + i) * 33 + tn] = ps[i];
    __syncthreads();
    if (tid < 64) {
        float sum = 0.f;
        #pragma unroll
        for (int t2 = 0; t2 < 32; ++t2) sum += red[tid * 33 + t2];
        part[((size_t)nc * SEQ + s) * 64 + tid] = sum;
    }
}

// ---------------------------------------------------------------------------
// K4: softmax over s per batch.  grid=64 (b), block=512 (s, 400 active).
// Sums the 4 n-chunk partials first.
// ---------------------------------------------------------------------------
__global__ __launch_bounds__(512) void k4_softmax(
    const float* __restrict__ part, float* __restrict__ attn_out)
{
    const int b = blockIdx.x;
    const int t = threadIdx.x;
    __shared__ float red[8];
    __shared__ float smax, ssum;
    float myv = 0.f, val = -1e30f;
    if (t < SEQ) {
        myv = part[((size_t)0 * SEQ + t) * 64 + b]
            + part[((size_t)1 * SEQ + t) * 64 + b]
            + part[((size_t)2 * SEQ + t) * 64 + b]
            + part[((size_t)3 * SEQ + t) * 64 + b];
        val = myv;
    }
    float m = val;
    #pragma unroll
    for (int off = 32; off > 0; off >>= 1) m = fmaxf(m, __shfl_down(m, off, 64));
    if ((t & 63) == 0) red[t >> 6] = m;
    __syncthreads();
    if (t == 0) {
        float mm = red[0];
        #pragma unroll
        for (int w = 1; w < 8; ++w) mm = fmaxf(mm, red[w]);
        smax = mm;
    }
    __syncthreads();
    float e = (t < SEQ) ? expf(myv - smax) : 0.f;
    float ssv = e;
    #pragma unroll
    for (int off = 32; off > 0; off >>= 1) ssv += __shfl_down(ssv, off, 64);
    if ((t & 63) == 0) red[t >> 6] = ssv;
    __syncthreads();
    if (t == 0) {
        float ss = 0.f;
        #pragma unroll
        for (int w = 0; w < 8; ++w) ss += red[w];
        ssum = ss;
    }
    __syncthreads();
    if (t < SEQ) attn_out[t * 64 + b] = e / ssum;
}

// ---------------------------------------------------------------------------
// K5: context[b,h] = sum_s attn[s,b] * enc[s,b,h].  grid=(64 b, 4 h-chunks),
// block=128.  enc rows coalesced; attn[.,b] staged in LDS.
// ---------------------------------------------------------------------------
__global__ __launch_bounds__(128) void k5_context(
    const float* __restrict__ enc, const float* __restrict__ attn,
    float* __restrict__ ctx)
{
    const int b  = blockIdx.x;
    const int hc = blockIdx.y;
    const int t  = threadIdx.x;
    __shared__ float a_s[SEQ];
    for (int s = t; s < SEQ; s += 128) a_s[s] = attn[s * 64 + b];
    __syncthreads();
    const int hh = hc * 128 + t;
    float acc = 0.f;
    #pragma unroll 4
    for (int s = 0; s < SEQ; ++s)
        acc += a_s[s] * enc[((size_t)s * 64 + b) * H + hh];
    ctx[b * H + hh] = acc;
}

// ---------------------------------------------------------------------------
// K5b: p[b] = sigmoid(ctx.pWh + pd).  grid=64, block=64 (one wave).
// ---------------------------------------------------------------------------
__global__ __launch_bounds__(64) void k5b_p(
    const float* __restrict__ ctx, const float* __restrict__ pWh,
    const float* __restrict__ pd, float* __restrict__ p_out,
    float* __restrict__ p_ws)
{
    const int b = blockIdx.x;
    const int t = threadIdx.x;
    float pp = 0.f;
    #pragma unroll
    for (int k = t; k < H; k += 64) pp += ctx[b * H + k] * pWh[k];
    #pragma unroll
    for (int off = 32; off > 0; off >>= 1) pp += __shfl_down(pp, off, 64);
    if (t == 0) {
        float pv = 1.f / (1.f + expf(-(pp + pd[b])));
        p_out[b] = pv;
        p_ws[b]  = pv;
    }
}

// ---------------------------------------------------------------------------
// K6: ext[b, v] = p[b] * selu(gs[b] . out_W[v] + out_b[v]),  gs = [h | ctx].
// grid = ceil(V/64) blocks; block 256 = 4 waves; wave -> 16 consecutive v,
// lane -> b.  W rows wave-uniform (broadcast, float4); gs staged in LDS.
// HBM floor: out_W 204.8 MB.
// ---------------------------------------------------------------------------
__global__ __launch_bounds__(256) void k6_vocab(
    const float* __restrict__ h, const float* __restrict__ ctx,
    const float* __restrict__ outW, const float* __restrict__ outb,
    const float* __restrict__ p_ws, float* __restrict__ ext)
{
    __shared__ float gss[64][68];
    const int tid  = threadIdx.x;
    const int wave = tid >> 6;
    const int lane = tid & 63;            // = b
    const int v0   = blockIdx.x * 64 + wave * 16;
    const bool wvalid = (v0 < V);         // last block: waves 1..3 invalid
    const float* wbase = outW + (size_t)(wvalid ? v0 : 0) * H2;

    float acc[16];
    #pragma unroll
    for (int i = 0; i < 16; ++i) acc[i] = 0.f;

    for (int kc = 0; kc < H2; kc += 64) {
        __syncthreads();
        #pragma unroll
        for (int e = tid; e < 4096; e += 256) {
            int bb = e >> 6, kk = e & 63;
            int k = kc + kk;
            gss[bb][kk] = (k < H) ? h[bb * H + k] : ctx[bb * H + (k - H)];
        }
        __syncthreads();
        #pragma unroll 4
        for (int kk = 0; kk < 64; kk += 4) {
            float4 g = *(const float4*)&gss[lane][kk];
            #pragma unroll
            for (int i = 0; i < 16; ++i) {
                float4 w = *(const float4*)&wbase[(size_t)i * H2 + kc + kk];
                acc[i] += g.x * w.x + g.y * w.y + g.z * w.z + g.w * w.w;
            }
        }
    }
    if (wvalid) {
        const float pv = p_ws[lane];
        float res[16];
        #pragma unroll
        for (int i = 0; i < 16; ++i) {
            float zz = acc[i] + outb[v0 + i];
            float sv = (zz > 0.f) ? 1.0507009873554805f * zz
                                  : 1.7580993408473766f * (expf(zz) - 1.f);
            res[i] = pv * sv;
        }
        float* dst = ext + (size_t)lane * EXT + v0;
        #pragma unroll
        for (int q = 0; q < 4; ++q)
            *(float4*)&dst[q * 4] =
                make_float4(res[4 * q], res[4 * q + 1], res[4 * q + 2], res[4 * q + 3]);
    }
}

// ---------------------------------------------------------------------------
// K7: oov tail of extended distribution.
// ---------------------------------------------------------------------------
__global__ __launch_bounds__(256) void k7_oov(
    const float* __restrict__ attn, const int* __restrict__ mask,
    const float* __restrict__ p_ws, float* __restrict__ ext)
{
    int e = blockIdx.x * 256 + threadIdx.x;
    if (e < SEQ * 64) {
        int s = e >> 6, b = e & 63;
        float val = (1.f - p_ws[b]) * attn[e] * (mask[e] ? 1.f : 0.f);
        ext[(size_t)b * EXT + V + s] = val;
    }
}

// ---------------------------------------------------------------------------
extern "C" void kernel_launch(void* const* d_in, const int* in_sizes, int n_in,
                              void* d_out, int out_size, void* d_ws, size_t ws_size,
                              hipStream_t stream)
{
    (void)in_sizes; (void)n_in; (void)out_size; (void)ws_size;
    const float* x      = (const float*)d_in[0];
    const float* enc    = (const float*)d_in[1];
    const int*   mask   = (const int*)  d_in[2];
    const float* h0     = (const float*)d_in[3];
    const float* W_ih   = (const float*)d_in[4];
    const float* W_hh   = (const float*)d_in[5];
    const float* b_ih   = (const float*)d_in[6];
    const float* b_hh   = (const float*)d_in[7];
    const float* outW   = (const float*)d_in[8];
    const float* outb   = (const float*)d_in[9];
    const float* v      = (const float*)d_in[10];
    const float* Wh     = (const float*)d_in[11];
    const float* Ws     = (const float*)d_in[12];
    const float* b_attn = (const float*)d_in[13];
    const float* pWh    = (const float*)d_in[14];
    const float* pWs    = (const float*)d_in[15];
    const float* pWx    = (const float*)d_in[16];
    const float* pWx_b  = (const float*)d_in[17];

    float* out        = (float*)d_out;
    float* out_ext    = out;                           // 64 x 50400
    float* out_hidden = out + (size_t)64 * EXT;        // 64 x 512
    float* out_p      = out_hidden + 64 * H;           // 64
    float* out_attn   = out_p + 64;                    // 400 x 64

    float* ws      = (float*)d_ws;                     // 672 KB total
    float* ws_x2   = ws;                               // 64*512
    float* ws_pd   = ws_x2 + 64 * H;                   // 64
    float* ws_part = ws_pd + 64;                       // 4*400*64
    float* ws_ctx  = ws_part + 4 * SEQ * 64;           // 64*512
    float* ws_p    = ws_ctx + 64 * H;                  // 64

    k1_gru<<<128, 256, 0, stream>>>(x, h0, W_ih, W_hh, b_ih, b_hh, out_hidden);
    k2_post<<<64, 512, 0, stream>>>(out_hidden, Ws, b_attn, x, pWs, pWx, pWx_b,
                                    ws_x2, ws_pd);
    k3_scores<<<dim3(SEQ, 4), 256, 0, stream>>>(enc, Wh, ws_x2, v, ws_part);
    k4_softmax<<<64, 512, 0, stream>>>(ws_part, out_attn);
    k5_context<<<dim3(64, 4), 128, 0, stream>>>(enc, out_attn, ws_ctx);
    k5b_p<<<64, 64, 0, stream>>>(ws_ctx, pWh, ws_pd, out_p, ws_p);
    k6_vocab<<<(V + 63) / 64, 256, 0, stream>>>(out_hidden, ws_ctx, outW, outb,
                                                ws_p, out_ext);
    k7_oov<<<(SEQ * 64 + 255) / 256, 256, 0, stream>>>(out_attn, mask, ws_p, out_ext);
}

// Round 2
// 826.926 us; speedup vs baseline: 1.4899x; 1.4899x over previous
//
#include <hip/hip_runtime.h>
#include <cmath>

#define H    512
#define H2   1024
#define H3   1536
#define V    50000
#define SEQ  400
#define BATCH 64
#define EXT  (V + SEQ)   // 50400

// ---------------------------------------------------------------------------
// K1: single-step GRU.  grid=128 blocks x 256 thr.  wave -> column j (512 of
// them), lane -> batch b.  (known issue: wave-uniform W loads; small data,
// revisit if it shows up in top-5 next round)
// ---------------------------------------------------------------------------
__global__ __launch_bounds__(256) void k1_gru(
    const float* __restrict__ x, const float* __restrict__ h0,
    const float* __restrict__ W_ih, const float* __restrict__ W_hh,
    const float* __restrict__ b_ih, const float* __restrict__ b_hh,
    float* __restrict__ h_out)
{
    __shared__ float xs[64][68];
    __shared__ float hs[64][68];
    const int tid  = threadIdx.x;
    const int j    = blockIdx.x * 4 + (tid >> 6);
    const int lane = tid & 63;

    float a_ir = 0.f, a_iz = 0.f, a_in = 0.f, a_hr = 0.f, a_hz = 0.f, a_hn = 0.f;
    const float* wr_i = W_ih + (size_t)j * H;
    const float* wz_i = W_ih + (size_t)(H + j) * H;
    const float* wn_i = W_ih + (size_t)(2 * H + j) * H;
    const float* wr_h = W_hh + (size_t)j * H;
    const float* wz_h = W_hh + (size_t)(H + j) * H;
    const float* wn_h = W_hh + (size_t)(2 * H + j) * H;

    for (int kc = 0; kc < H; kc += 64) {
        __syncthreads();
        #pragma unroll
        for (int e = tid; e < 64 * 64; e += 256) {
            int bb = e >> 6, kk = e & 63;
            xs[bb][kk] = x[bb * H + kc + kk];
            hs[bb][kk] = h0[bb * H + kc + kk];
        }
        __syncthreads();
        #pragma unroll
        for (int kk = 0; kk < 64; kk += 4) {
            float4 xv = *(const float4*)&xs[lane][kk];
            float4 hv = *(const float4*)&hs[lane][kk];
            float4 w;
            w = *(const float4*)&wr_i[kc + kk];
            a_ir += w.x * xv.x + w.y * xv.y + w.z * xv.z + w.w * xv.w;
            w = *(const float4*)&wz_i[kc + kk];
            a_iz += w.x * xv.x + w.y * xv.y + w.z * xv.z + w.w * xv.w;
            w = *(const float4*)&wn_i[kc + kk];
            a_in += w.x * xv.x + w.y * xv.y + w.z * xv.z + w.w * xv.w;
            w = *(const float4*)&wr_h[kc + kk];
            a_hr += w.x * hv.x + w.y * hv.y + w.z * hv.z + w.w * hv.w;
            w = *(const float4*)&wz_h[kc + kk];
            a_hz += w.x * hv.x + w.y * hv.y + w.z * hv.z + w.w * hv.w;
            w = *(const float4*)&wn_h[kc + kk];
            a_hn += w.x * hv.x + w.y * hv.y + w.z * hv.z + w.w * hv.w;
        }
    }
    float r = 1.f / (1.f + expf(-(a_ir + b_ih[j] + a_hr + b_hh[j])));
    float z = 1.f / (1.f + expf(-(a_iz + b_ih[H + j] + a_hz + b_hh[H + j])));
    float n = tanhf(a_in + b_ih[2 * H + j] + r * (a_hn + b_hh[2 * H + j]));
    float h0v = h0[lane * H + j];
    h_out[lane * H + j] = (1.f - z) * n + z * h0v;
}

// ---------------------------------------------------------------------------
// K2: x2 = h @ Ws + b_attn, plus p partial  pd[b] = h.pWs + x.pWx + pWx_b.
// ---------------------------------------------------------------------------
__global__ __launch_bounds__(512) void k2_post(
    const float* __restrict__ h, const float* __restrict__ Ws,
    const float* __restrict__ b_attn, const float* __restrict__ x,
    const float* __restrict__ pWs, const float* __restrict__ pWx,
    const float* __restrict__ pWx_b,
    float* __restrict__ x2, float* __restrict__ pd)
{
    const int b = blockIdx.x;
    const int k = threadIdx.x;
    __shared__ float hsh[H];
    __shared__ float rbuf[8];
    hsh[k] = h[b * H + k];
    __syncthreads();
    float acc = 0.f;
    #pragma unroll 8
    for (int m = 0; m < H; ++m) acc += hsh[m] * Ws[(size_t)m * H + k];
    x2[b * H + k] = acc + b_attn[k];

    float pp = hsh[k] * pWs[k] + x[b * H + k] * pWx[k];
    #pragma unroll
    for (int off = 32; off > 0; off >>= 1) pp += __shfl_down(pp, off, 64);
    if ((k & 63) == 0) rbuf[k >> 6] = pp;
    __syncthreads();
    if (k == 0) {
        float t = pWx_b[0];
        #pragma unroll
        for (int w = 0; w < 8; ++w) t += rbuf[w];
        pd[b] = t;
    }
}

// ---------------------------------------------------------------------------
// K3 v2: score GEMM M=64(b) x N=128(n) x K=512 per block, grid (400 s, 4 nc).
// 16x16 thread grid; thread tile 4b x 8n (n strided by 16 for bank spread);
// A [b][kk] natural, B transposed [n][kk]; K-vectorized float4 LDS reads ->
// 12 ds_read_b128 per 128 FMA = VALU-bound. Fused tanh*v epilogue, shfl
// reduce over tn, float4 partial store.
// ---------------------------------------------------------------------------
__global__ __launch_bounds__(256) void k3_scores(
    const float* __restrict__ enc, const float* __restrict__ Wh,
    const float* __restrict__ x2, const float* __restrict__ v,
    float* __restrict__ part)
{
    __shared__ float As[64][68];    // [b][kk]
    __shared__ float Bt[128][68];   // [n][kk]  (transposed Wh slice)
    const int s   = blockIdx.x;
    const int nc  = blockIdx.y;
    const int n0  = nc * 128;
    const int tid = threadIdx.x;
    const int tn  = tid & 15;
    const int tb  = tid >> 4;

    float acc[4][8];
    #pragma unroll
    for (int bi = 0; bi < 4; ++bi)
        #pragma unroll
        for (int i = 0; i < 8; ++i) acc[bi][i] = 0.f;

    const float* A = enc + (size_t)s * 64 * H;
    for (int kc = 0; kc < H; kc += 64) {
        __syncthreads();
        #pragma unroll
        for (int e = tid; e < 1024; e += 256) {        // A: 64b x 64k, float4
            int bb = e >> 4, kq = e & 15;
            *(float4*)&As[bb][kq * 4] = *(const float4*)&A[bb * H + kc + kq * 4];
        }
        #pragma unroll
        for (int e = tid; e < 8192; e += 256) {        // B: transpose-stage
            int kk = e >> 7, nn = e & 127;
            Bt[nn][kk] = Wh[(size_t)(kc + kk) * H + n0 + nn];
        }
        __syncthreads();
        #pragma unroll 2
        for (int kk = 0; kk < 64; kk += 4) {
            float4 g[4], w[8];
            #pragma unroll
            for (int bi = 0; bi < 4; ++bi)
                g[bi] = *(const float4*)&As[tb * 4 + bi][kk];
            #pragma unroll
            for (int i = 0; i < 8; ++i)
                w[i] = *(const float4*)&Bt[tn + 16 * i][kk];
            #pragma unroll
            for (int bi = 0; bi < 4; ++bi)
                #pragma unroll
                for (int i = 0; i < 8; ++i)
                    acc[bi][i] += g[bi].x * w[i].x + g[bi].y * w[i].y
                                + g[bi].z * w[i].z + g[bi].w * w[i].w;
        }
    }
    // fused epilogue: tanh(acc + x2)*v, sum this thread's 8 n
    float psum[4];
    #pragma unroll
    for (int bi = 0; bi < 4; ++bi) {
        const int b = tb * 4 + bi;
        float ssv = 0.f;
        #pragma unroll
        for (int i = 0; i < 8; ++i) {
            const int n = n0 + tn + 16 * i;
            ssv += tanhf(acc[bi][i] + x2[b * H + n]) * v[n];
        }
        psum[bi] = ssv;
    }
    #pragma unroll
    for (int bi = 0; bi < 4; ++bi) {
        float xv = psum[bi];
        #pragma unroll
        for (int off = 8; off > 0; off >>= 1) xv += __shfl_down(xv, off, 16);
        psum[bi] = xv;
    }
    if (tn == 0) {
        *(float4*)&part[((size_t)nc * SEQ + s) * 64 + tb * 4] =
            make_float4(psum[0], psum[1], psum[2], psum[3]);
    }
}

// ---------------------------------------------------------------------------
// K4: softmax over s per batch.  grid=64 (b), block=512 (s, 400 active).
// ---------------------------------------------------------------------------
__global__ __launch_bounds__(512) void k4_softmax(
    const float* __restrict__ part, float* __restrict__ attn_out)
{
    const int b = blockIdx.x;
    const int t = threadIdx.x;
    __shared__ float red[8];
    __shared__ float smax, ssum;
    float myv = 0.f, val = -1e30f;
    if (t < SEQ) {
        myv = part[((size_t)0 * SEQ + t) * 64 + b]
            + part[((size_t)1 * SEQ + t) * 64 + b]
            + part[((size_t)2 * SEQ + t) * 64 + b]
            + part[((size_t)3 * SEQ + t) * 64 + b];
        val = myv;
    }
    float m = val;
    #pragma unroll
    for (int off = 32; off > 0; off >>= 1) m = fmaxf(m, __shfl_down(m, off, 64));
    if ((t & 63) == 0) red[t >> 6] = m;
    __syncthreads();
    if (t == 0) {
        float mm = red[0];
        #pragma unroll
        for (int w = 1; w < 8; ++w) mm = fmaxf(mm, red[w]);
        smax = mm;
    }
    __syncthreads();
    float e = (t < SEQ) ? expf(myv - smax) : 0.f;
    float ssv = e;
    #pragma unroll
    for (int off = 32; off > 0; off >>= 1) ssv += __shfl_down(ssv, off, 64);
    if ((t & 63) == 0) red[t >> 6] = ssv;
    __syncthreads();
    if (t == 0) {
        float ss = 0.f;
        #pragma unroll
        for (int w = 0; w < 8; ++w) ss += red[w];
        ssum = ss;
    }
    __syncthreads();
    if (t < SEQ) attn_out[t * 64 + b] = e / ssum;
}

// ---------------------------------------------------------------------------
// K5: context[b,h] = sum_s attn[s,b] * enc[s,b,h].
// ---------------------------------------------------------------------------
__global__ __launch_bounds__(128) void k5_context(
    const float* __restrict__ enc, const float* __restrict__ attn,
    float* __restrict__ ctx)
{
    const int b  = blockIdx.x;
    const int hc = blockIdx.y;
    const int t  = threadIdx.x;
    __shared__ float a_s[SEQ];
    for (int s = t; s < SEQ; s += 128) a_s[s] = attn[s * 64 + b];
    __syncthreads();
    const int hh = hc * 128 + t;
    float acc = 0.f;
    #pragma unroll 4
    for (int s = 0; s < SEQ; ++s)
        acc += a_s[s] * enc[((size_t)s * 64 + b) * H + hh];
    ctx[b * H + hh] = acc;
}

// ---------------------------------------------------------------------------
// K5b: p[b] = sigmoid(ctx.pWh + pd).
// ---------------------------------------------------------------------------
__global__ __launch_bounds__(64) void k5b_p(
    const float* __restrict__ ctx, const float* __restrict__ pWh,
    const float* __restrict__ pd, float* __restrict__ p_out,
    float* __restrict__ p_ws)
{
    const int b = blockIdx.x;
    const int t = threadIdx.x;
    float pp = 0.f;
    #pragma unroll
    for (int k = t; k < H; k += 64) pp += ctx[b * H + k] * pWh[k];
    #pragma unroll
    for (int off = 32; off > 0; off >>= 1) pp += __shfl_down(pp, off, 64);
    if (t == 0) {
        float pv = 1.f / (1.f + expf(-(pp + pd[b])));
        p_out[b] = pv;
        p_ws[b]  = pv;
    }
}

// ---------------------------------------------------------------------------
// K6 v2: ext[b,v] = p[b]*selu(gs[b].out_W[v] + out_b[v]).  Proper coalesced
// GEMM: grid 782 blocks of 64 vocab rows; 16x16 thread grid, thread tile
// 4b x 4v (v strided by 16 -> LDS reads spread all 32 banks); gs and W tiles
// staged coalesced (float4); 8 ds_read_b128 per 64 FMA = VALU-bound.
// Floors: compute 42 us, HBM (204.8 MB out_W) 33 us.
// ---------------------------------------------------------------------------
__global__ __launch_bounds__(256) void k6_vocab(
    const float* __restrict__ h, const float* __restrict__ ctx,
    const float* __restrict__ outW, const float* __restrict__ outb,
    const float* __restrict__ p_ws, float* __restrict__ ext)
{
    __shared__ float gst[64][68];   // [b][kk]
    __shared__ float wt[64][68];    // [v_local][kk]
    const int tid = threadIdx.x;
    const int tv  = tid & 15;
    const int tb  = tid >> 4;
    const int v0  = blockIdx.x * 64;

    float acc[4][4];
    #pragma unroll
    for (int bi = 0; bi < 4; ++bi)
        #pragma unroll
        for (int i = 0; i < 4; ++i) acc[bi][i] = 0.f;

    for (int kc = 0; kc < H2; kc += 64) {
        __syncthreads();
        const float* src = (kc < H) ? (h + kc) : (ctx + (kc - H));
        #pragma unroll
        for (int e = tid; e < 1024; e += 256) {        // gs: 64b x 64k
            int bb = e >> 4, kq = e & 15;
            *(float4*)&gst[bb][kq * 4] = *(const float4*)&src[bb * H + kq * 4];
        }
        #pragma unroll
        for (int e = tid; e < 1024; e += 256) {        // W: 64v x 64k
            int vv = e >> 4, kq = e & 15;
            int vr = v0 + vv; if (vr >= V) vr = V - 1;
            *(float4*)&wt[vv][kq * 4] =
                *(const float4*)&outW[(size_t)vr * H2 + kc + kq * 4];
        }
        __syncthreads();
        #pragma unroll 2
        for (int kk = 0; kk < 64; kk += 4) {
            float4 g[4], w[4];
            #pragma unroll
            for (int bi = 0; bi < 4; ++bi)
                g[bi] = *(const float4*)&gst[tb * 4 + bi][kk];
            #pragma unroll
            for (int i = 0; i < 4; ++i)
                w[i] = *(const float4*)&wt[tv + 16 * i][kk];
            #pragma unroll
            for (int bi = 0; bi < 4; ++bi)
                #pragma unroll
                for (int i = 0; i < 4; ++i)
                    acc[bi][i] += g[bi].x * w[i].x + g[bi].y * w[i].y
                                + g[bi].z * w[i].z + g[bi].w * w[i].w;
        }
    }
    #pragma unroll
    for (int bi = 0; bi < 4; ++bi) {
        const int b = tb * 4 + bi;
        const float pv = p_ws[b];
        #pragma unroll
        for (int i = 0; i < 4; ++i) {
            const int vv = v0 + tv + 16 * i;
            if (vv < V) {
                float zz = acc[bi][i] + outb[vv];
                float sv = (zz > 0.f) ? 1.0507009873554805f * zz
                                      : 1.7580993408473766f * (expf(zz) - 1.f);
                ext[(size_t)b * EXT + vv] = pv * sv;
            }
        }
    }
}

// ---------------------------------------------------------------------------
// K7: oov tail of extended distribution.
// ---------------------------------------------------------------------------
__global__ __launch_bounds__(256) void k7_oov(
    const float* __restrict__ attn, const int* __restrict__ mask,
    const float* __restrict__ p_ws, float* __restrict__ ext)
{
    int e = blockIdx.x * 256 + threadIdx.x;
    if (e < SEQ * 64) {
        int s = e >> 6, b = e & 63;
        float val = (1.f - p_ws[b]) * attn[e] * (mask[e] ? 1.f : 0.f);
        ext[(size_t)b * EXT + V + s] = val;
    }
}

// ---------------------------------------------------------------------------
extern "C" void kernel_launch(void* const* d_in, const int* in_sizes, int n_in,
                              void* d_out, int out_size, void* d_ws, size_t ws_size,
                              hipStream_t stream)
{
    (void)in_sizes; (void)n_in; (void)out_size; (void)ws_size;
    const float* x      = (const float*)d_in[0];
    const float* enc    = (const float*)d_in[1];
    const int*   mask   = (const int*)  d_in[2];
    const float* h0     = (const float*)d_in[3];
    const float* W_ih   = (const float*)d_in[4];
    const float* W_hh   = (const float*)d_in[5];
    const float* b_ih   = (const float*)d_in[6];
    const float* b_hh   = (const float*)d_in[7];
    const float* outW   = (const float*)d_in[8];
    const float* outb   = (const float*)d_in[9];
    const float* v      = (const float*)d_in[10];
    const float* Wh     = (const float*)d_in[11];
    const float* Ws     = (const float*)d_in[12];
    const float* b_attn = (const float*)d_in[13];
    const float* pWh    = (const float*)d_in[14];
    const float* pWs    = (const float*)d_in[15];
    const float* pWx    = (const float*)d_in[16];
    const float* pWx_b  = (const float*)d_in[17];

    float* out        = (float*)d_out;
    float* out_ext    = out;                           // 64 x 50400
    float* out_hidden = out + (size_t)64 * EXT;        // 64 x 512
    float* out_p      = out_hidden + 64 * H;           // 64
    float* out_attn   = out_p + 64;                    // 400 x 64

    float* ws      = (float*)d_ws;
    float* ws_x2   = ws;                               // 64*512
    float* ws_pd   = ws_x2 + 64 * H;                   // 64
    float* ws_part = ws_pd + 64;                       // 4*400*64
    float* ws_ctx  = ws_part + 4 * SEQ * 64;           // 64*512
    float* ws_p    = ws_ctx + 64 * H;                  // 64

    k1_gru<<<128, 256, 0, stream>>>(x, h0, W_ih, W_hh, b_ih, b_hh, out_hidden);
    k2_post<<<64, 512, 0, stream>>>(out_hidden, Ws, b_attn, x, pWs, pWx, pWx_b,
                                    ws_x2, ws_pd);
    k3_scores<<<dim3(SEQ, 4), 256, 0, stream>>>(enc, Wh, ws_x2, v, ws_part);
    k4_softmax<<<64, 512, 0, stream>>>(ws_part, out_attn);
    k5_context<<<dim3(64, 4), 128, 0, stream>>>(enc, out_attn, ws_ctx);
    k5b_p<<<64, 64, 0, stream>>>(ws_ctx, pWh, ws_pd, out_p, ws_p);
    k6_vocab<<<(V + 63) / 64, 256, 0, stream>>>(out_hidden, ws_ctx, outW, outb,
                                                ws_p, out_ext);
    k7_oov<<<(SEQ * 64 + 255) / 256, 256, 0, stream>>>(out_attn, mask, ws_p, out_ext);
}

// Round 3
// 556.798 us; speedup vs baseline: 2.2128x; 1.4851x over previous
//
#include <hip/hip_runtime.h>
#include <cmath>

#define H    512
#define H2   1024
#define V    50000
#define SEQ  400
#define EXT  (V + SEQ)   // 50400

typedef __attribute__((ext_vector_type(8))) short short8;
typedef __attribute__((ext_vector_type(4))) float floatx4;

__device__ __forceinline__ unsigned short f2bf(float f) {
    unsigned int u = __float_as_uint(f);
    u += 0x7fffu + ((u >> 16) & 1u);      // round-to-nearest-even
    return (unsigned short)(u >> 16);
}

__device__ __forceinline__ uint4 pack8(float4 a, float4 b) {
    union { unsigned short s[8]; uint4 v; } r;
    r.s[0] = f2bf(a.x); r.s[1] = f2bf(a.y); r.s[2] = f2bf(a.z); r.s[3] = f2bf(a.w);
    r.s[4] = f2bf(b.x); r.s[5] = f2bf(b.y); r.s[6] = f2bf(b.z); r.s[7] = f2bf(b.w);
    return r.v;
}

// ---------------------------------------------------------------------------
// K0: WhT[n][k] = bf16(Wh[k][n]).  grid (8,8), 64x64 tiles, LDS transpose.
// One-time prep so k3's B staging is a straight bf16 16B-granule copy.
// ---------------------------------------------------------------------------
__global__ __launch_bounds__(256) void k0_transpose(
    const float* __restrict__ Wh, unsigned short* __restrict__ WhT)
{
    __shared__ float T[64][65];
    const int k0 = blockIdx.x * 64, n0 = blockIdx.y * 64;
    const int tid = threadIdx.x;
    #pragma unroll
    for (int i = 0; i < 16; ++i) {
        int e = i * 256 + tid;
        int r = e >> 6, c = e & 63;
        T[r][c] = Wh[(size_t)(k0 + r) * H + n0 + c];
    }
    __syncthreads();
    #pragma unroll
    for (int i = 0; i < 16; ++i) {
        int e = i * 256 + tid;
        int nn = e >> 6, kk = e & 63;
        WhT[(size_t)(n0 + nn) * H + k0 + kk] = f2bf(T[kk][nn]);
    }
}

// ---------------------------------------------------------------------------
// K1: single-step GRU (unchanged this round; revisit if it tops the profile).
// ---------------------------------------------------------------------------
__global__ __launch_bounds__(256) void k1_gru(
    const float* __restrict__ x, const float* __restrict__ h0,
    const float* __restrict__ W_ih, const float* __restrict__ W_hh,
    const float* __restrict__ b_ih, const float* __restrict__ b_hh,
    float* __restrict__ h_out)
{
    __shared__ float xs[64][68];
    __shared__ float hs[64][68];
    const int tid  = threadIdx.x;
    const int j    = blockIdx.x * 4 + (tid >> 6);
    const int lane = tid & 63;

    float a_ir = 0.f, a_iz = 0.f, a_in = 0.f, a_hr = 0.f, a_hz = 0.f, a_hn = 0.f;
    const float* wr_i = W_ih + (size_t)j * H;
    const float* wz_i = W_ih + (size_t)(H + j) * H;
    const float* wn_i = W_ih + (size_t)(2 * H + j) * H;
    const float* wr_h = W_hh + (size_t)j * H;
    const float* wz_h = W_hh + (size_t)(H + j) * H;
    const float* wn_h = W_hh + (size_t)(2 * H + j) * H;

    for (int kc = 0; kc < H; kc += 64) {
        __syncthreads();
        #pragma unroll
        for (int e = tid; e < 64 * 64; e += 256) {
            int bb = e >> 6, kk = e & 63;
            xs[bb][kk] = x[bb * H + kc + kk];
            hs[bb][kk] = h0[bb * H + kc + kk];
        }
        __syncthreads();
        #pragma unroll
        for (int kk = 0; kk < 64; kk += 4) {
            float4 xv = *(const float4*)&xs[lane][kk];
            float4 hv = *(const float4*)&hs[lane][kk];
            float4 w;
            w = *(const float4*)&wr_i[kc + kk];
            a_ir += w.x * xv.x + w.y * xv.y + w.z * xv.z + w.w * xv.w;
            w = *(const float4*)&wz_i[kc + kk];
            a_iz += w.x * xv.x + w.y * xv.y + w.z * xv.z + w.w * xv.w;
            w = *(const float4*)&wn_i[kc + kk];
            a_in += w.x * xv.x + w.y * xv.y + w.z * xv.z + w.w * xv.w;
            w = *(const float4*)&wr_h[kc + kk];
            a_hr += w.x * hv.x + w.y * hv.y + w.z * hv.z + w.w * hv.w;
            w = *(const float4*)&wz_h[kc + kk];
            a_hz += w.x * hv.x + w.y * hv.y + w.z * hv.z + w.w * hv.w;
            w = *(const float4*)&wn_h[kc + kk];
            a_hn += w.x * hv.x + w.y * hv.y + w.z * hv.z + w.w * hv.w;
        }
    }
    float r = 1.f / (1.f + expf(-(a_ir + b_ih[j] + a_hr + b_hh[j])));
    float z = 1.f / (1.f + expf(-(a_iz + b_ih[H + j] + a_hz + b_hh[H + j])));
    float n = tanhf(a_in + b_ih[2 * H + j] + r * (a_hn + b_hh[2 * H + j]));
    float h0v = h0[lane * H + j];
    h_out[lane * H + j] = (1.f - z) * n + z * h0v;
}

// ---------------------------------------------------------------------------
// K2: x2 = h @ Ws + b_attn, plus pd[b] = h.pWs + x.pWx + pWx_b.  (unchanged)
// ---------------------------------------------------------------------------
__global__ __launch_bounds__(512) void k2_post(
    const float* __restrict__ h, const float* __restrict__ Ws,
    const float* __restrict__ b_attn, const float* __restrict__ x,
    const float* __restrict__ pWs, const float* __restrict__ pWx,
    const float* __restrict__ pWx_b,
    float* __restrict__ x2, float* __restrict__ pd)
{
    const int b = blockIdx.x;
    const int k = threadIdx.x;
    __shared__ float hsh[H];
    __shared__ float rbuf[8];
    hsh[k] = h[b * H + k];
    __syncthreads();
    float acc = 0.f;
    #pragma unroll 8
    for (int m = 0; m < H; ++m) acc += hsh[m] * Ws[(size_t)m * H + k];
    x2[b * H + k] = acc + b_attn[k];

    float pp = hsh[k] * pWs[k] + x[b * H + k] * pWx[k];
    #pragma unroll
    for (int off = 32; off > 0; off >>= 1) pp += __shfl_down(pp, off, 64);
    if ((k & 63) == 0) rbuf[k >> 6] = pp;
    __syncthreads();
    if (k == 0) {
        float t = pWx_b[0];
        #pragma unroll
        for (int w = 0; w < 8; ++w) t += rbuf[w];
        pd[b] = t;
    }
}

// ---------------------------------------------------------------------------
// K3 v3 (MFMA): per block M=64(b) x N=128 x K=512, grid (400 s, 4 nc).
// mfma_f32_16x16x32_bf16.  LDS holds bf16 tiles as 16B granules with XOR
// swizzle  granule(row,k8) = row*8 + (k8 ^ (row&7))  -> staging writes are
// lane-linear (conflict-free) and fragment ds_read_b128 spread uniformly
// over all 32 banks.  A (enc) converted fp32->bf16 in staging; B read from
// pre-transposed bf16 WhT.  Fused tanh*v epilogue -> part[nc][s][64].
// Fragment maps (measured, m89/m120): A m=lane&15,k=q*8+j; B n=lane&15;
// C/D col=lane&15,row=q*4+reg.
// ---------------------------------------------------------------------------
__global__ __launch_bounds__(256) void k3_scores(
    const float* __restrict__ enc, const unsigned short* __restrict__ WhT,
    const float* __restrict__ x2, const float* __restrict__ v,
    float* __restrict__ part)
{
    __shared__ uint4 AsG[512];    // 64 m  x 8 k-granules
    __shared__ uint4 BsG[1024];   // 128 n x 8 k-granules
    __shared__ float red[4 * 64];
    const int s   = blockIdx.x;
    const int nc  = blockIdx.y;
    const int n0  = nc * 128;
    const int tid  = threadIdx.x;
    const int wave = tid >> 6;
    const int lane = tid & 63;
    const int lrow = lane & 15;
    const int q    = lane >> 4;

    floatx4 acc[4][2];
    #pragma unroll
    for (int mt = 0; mt < 4; ++mt)
        #pragma unroll
        for (int nt = 0; nt < 2; ++nt)
            acc[mt][nt] = (floatx4){0.f, 0.f, 0.f, 0.f};

    const float* Abase = enc + (size_t)s * 64 * H;
    for (int kc = 0; kc < H; kc += 64) {
        __syncthreads();
        #pragma unroll
        for (int c = 0; c < 2; ++c) {           // A: cvt fp32->bf16
            int idx = c * 256 + tid;
            int m = idx >> 3, j = idx & 7, k8 = j ^ (m & 7);
            const float* src = Abase + m * H + kc + k8 * 8;
            AsG[idx] = pack8(*(const float4*)src, *(const float4*)(src + 4));
        }
        #pragma unroll
        for (int c = 0; c < 4; ++c) {           // B: straight bf16 granules
            int idx = c * 256 + tid;
            int n = idx >> 3, j = idx & 7, k8 = j ^ (n & 7);
            BsG[idx] = *(const uint4*)(WhT + (size_t)(n0 + n) * H + kc + k8 * 8);
        }
        __syncthreads();
        #pragma unroll
        for (int kk8 = 0; kk8 < 8; kk8 += 4) {
            const int k8 = kk8 + q;
            short8 a[4], b[2];
            #pragma unroll
            for (int mt = 0; mt < 4; ++mt) {
                int m = mt * 16 + lrow;
                a[mt] = *(const short8*)&AsG[m * 8 + (k8 ^ (m & 7))];
            }
            #pragma unroll
            for (int nt = 0; nt < 2; ++nt) {
                int n = wave * 32 + nt * 16 + lrow;
                b[nt] = *(const short8*)&BsG[n * 8 + (k8 ^ (n & 7))];
            }
            #pragma unroll
            for (int mt = 0; mt < 4; ++mt)
                #pragma unroll
                for (int nt = 0; nt < 2; ++nt)
                    acc[mt][nt] = __builtin_amdgcn_mfma_f32_16x16x32_bf16(
                        a[mt], b[nt], acc[mt][nt], 0, 0, 0);
        }
    }
    // epilogue: tanh(acc + x2)*v, reduce over this wave's 32 n via shfl(16)
    float val[4][4];
    #pragma unroll
    for (int mt = 0; mt < 4; ++mt) {
        #pragma unroll
        for (int r = 0; r < 4; ++r) {
            const int bb = mt * 16 + q * 4 + r;
            float sum = 0.f;
            #pragma unroll
            for (int nt = 0; nt < 2; ++nt) {
                const int n = n0 + wave * 32 + nt * 16 + lrow;
                sum += tanhf(acc[mt][nt][r] + x2[bb * H + n]) * v[n];
            }
            #pragma unroll
            for (int off = 8; off > 0; off >>= 1) sum += __shfl_down(sum, off, 16);
            val[mt][r] = sum;
        }
    }
    if (lrow == 0) {
        #pragma unroll
        for (int mt = 0; mt < 4; ++mt)
            #pragma unroll
            for (int r = 0; r < 4; ++r)
                red[wave * 64 + mt * 16 + q * 4 + r] = val[mt][r];
    }
    __syncthreads();
    if (tid < 64) {
        float sc = red[tid] + red[64 + tid] + red[128 + tid] + red[192 + tid];
        part[((size_t)nc * SEQ + s) * 64 + tid] = sc;
    }
}

// ---------------------------------------------------------------------------
// K4: softmax over s per batch.  (unchanged)
// ---------------------------------------------------------------------------
__global__ __launch_bounds__(512) void k4_softmax(
    const float* __restrict__ part, float* __restrict__ attn_out)
{
    const int b = blockIdx.x;
    const int t = threadIdx.x;
    __shared__ float red[8];
    __shared__ float smax, ssum;
    float myv = 0.f, val = -1e30f;
    if (t < SEQ) {
        myv = part[((size_t)0 * SEQ + t) * 64 + b]
            + part[((size_t)1 * SEQ + t) * 64 + b]
            + part[((size_t)2 * SEQ + t) * 64 + b]
            + part[((size_t)3 * SEQ + t) * 64 + b];
        val = myv;
    }
    float m = val;
    #pragma unroll
    for (int off = 32; off > 0; off >>= 1) m = fmaxf(m, __shfl_down(m, off, 64));
    if ((t & 63) == 0) red[t >> 6] = m;
    __syncthreads();
    if (t == 0) {
        float mm = red[0];
        #pragma unroll
        for (int w = 1; w < 8; ++w) mm = fmaxf(mm, red[w]);
        smax = mm;
    }
    __syncthreads();
    float e = (t < SEQ) ? expf(myv - smax) : 0.f;
    float ssv = e;
    #pragma unroll
    for (int off = 32; off > 0; off >>= 1) ssv += __shfl_down(ssv, off, 64);
    if ((t & 63) == 0) red[t >> 6] = ssv;
    __syncthreads();
    if (t == 0) {
        float ss = 0.f;
        #pragma unroll
        for (int w = 0; w < 8; ++w) ss += red[w];
        ssum = ss;
    }
    __syncthreads();
    if (t < SEQ) attn_out[t * 64 + b] = e / ssum;
}

// ---------------------------------------------------------------------------
// K5: context[b,h] = sum_s attn[s,b] * enc[s,b,h].  (unchanged)
// ---------------------------------------------------------------------------
__global__ __launch_bounds__(128) void k5_context(
    const float* __restrict__ enc, const float* __restrict__ attn,
    float* __restrict__ ctx)
{
    const int b  = blockIdx.x;
    const int hc = blockIdx.y;
    const int t  = threadIdx.x;
    __shared__ float a_s[SEQ];
    for (int s = t; s < SEQ; s += 128) a_s[s] = attn[s * 64 + b];
    __syncthreads();
    const int hh = hc * 128 + t;
    float acc = 0.f;
    #pragma unroll 4
    for (int s = 0; s < SEQ; ++s)
        acc += a_s[s] * enc[((size_t)s * 64 + b) * H + hh];
    ctx[b * H + hh] = acc;
}

// ---------------------------------------------------------------------------
// K5b: p[b] = sigmoid(ctx.pWh + pd).  (unchanged)
// ---------------------------------------------------------------------------
__global__ __launch_bounds__(64) void k5b_p(
    const float* __restrict__ ctx, const float* __restrict__ pWh,
    const float* __restrict__ pd, float* __restrict__ p_out,
    float* __restrict__ p_ws)
{
    const int b = blockIdx.x;
    const int t = threadIdx.x;
    float pp = 0.f;
    #pragma unroll
    for (int k = t; k < H; k += 64) pp += ctx[b * H + k] * pWh[k];
    #pragma unroll
    for (int off = 32; off > 0; off >>= 1) pp += __shfl_down(pp, off, 64);
    if (t == 0) {
        float pv = 1.f / (1.f + expf(-(pp + pd[b])));
        p_out[b] = pv;
        p_ws[b]  = pv;
    }
}

// ---------------------------------------------------------------------------
// K6 v3 (MFMA): ext[b,v] = p[b]*selu(gs[b].out_W[v]+out_b[v]).  Per block
// M=64(b) x N=64(v) x K=1024, grid 782.  out_W rows are k-contiguous ->
// no transpose; fp32->bf16 cvt in staging (out_W read exactly once: HBM
// floor 205 MB = 33 us dominates).  Same swizzled-granule scheme as k3.
// ---------------------------------------------------------------------------
__global__ __launch_bounds__(256) void k6_vocab(
    const float* __restrict__ h, const float* __restrict__ ctx,
    const float* __restrict__ outW, const float* __restrict__ outb,
    const float* __restrict__ p_ws, float* __restrict__ ext)
{
    __shared__ uint4 AsG[512];   // 64 b x 8 k-granules
    __shared__ uint4 BsG[512];   // 64 v x 8 k-granules
    __shared__ float p_l[64];
    const int tid  = threadIdx.x;
    const int wave = tid >> 6;
    const int lane = tid & 63;
    const int lrow = lane & 15;
    const int q    = lane >> 4;
    const int v0   = blockIdx.x * 64;

    if (tid < 64) p_l[tid] = p_ws[tid];

    floatx4 acc[4];
    #pragma unroll
    for (int mt = 0; mt < 4; ++mt) acc[mt] = (floatx4){0.f, 0.f, 0.f, 0.f};

    for (int kc = 0; kc < H2; kc += 64) {
        __syncthreads();
        const float* Ab = (kc < H) ? (h + kc) : (ctx + (kc - H));
        #pragma unroll
        for (int c = 0; c < 2; ++c) {           // gs: cvt fp32->bf16
            int idx = c * 256 + tid;
            int m = idx >> 3, j = idx & 7, k8 = j ^ (m & 7);
            const float* src = Ab + m * H + k8 * 8;
            AsG[idx] = pack8(*(const float4*)src, *(const float4*)(src + 4));
        }
        #pragma unroll
        for (int c = 0; c < 2; ++c) {           // out_W: cvt fp32->bf16
            int idx = c * 256 + tid;
            int n = idx >> 3, j = idx & 7, k8 = j ^ (n & 7);
            int vr = v0 + n; if (vr >= V) vr = V - 1;
            const float* src = outW + (size_t)vr * H2 + kc + k8 * 8;
            BsG[idx] = pack8(*(const float4*)src, *(const float4*)(src + 4));
        }
        __syncthreads();
        #pragma unroll
        for (int kk8 = 0; kk8 < 8; kk8 += 4) {
            const int k8 = kk8 + q;
            const int n = wave * 16 + lrow;
            short8 b = *(const short8*)&BsG[n * 8 + (k8 ^ (n & 7))];
            #pragma unroll
            for (int mt = 0; mt < 4; ++mt) {
                int m = mt * 16 + lrow;
                short8 a = *(const short8*)&AsG[m * 8 + (k8 ^ (m & 7))];
                acc[mt] = __builtin_amdgcn_mfma_f32_16x16x32_bf16(a, b, acc[mt], 0, 0, 0);
            }
        }
    }
    const int n = v0 + wave * 16 + lrow;
    if (n < V) {
        const float ob = outb[n];
        #pragma unroll
        for (int mt = 0; mt < 4; ++mt) {
            #pragma unroll
            for (int r = 0; r < 4; ++r) {
                const int bb = mt * 16 + q * 4 + r;
                float zz = acc[mt][r] + ob;
                float sv = (zz > 0.f) ? 1.0507009873554805f * zz
                                      : 1.7580993408473766f * (expf(zz) - 1.f);
                ext[(size_t)bb * EXT + n] = p_l[bb] * sv;
            }
        }
    }
}

// ---------------------------------------------------------------------------
// K7: oov tail.  (unchanged)
// ---------------------------------------------------------------------------
__global__ __launch_bounds__(256) void k7_oov(
    const float* __restrict__ attn, const int* __restrict__ mask,
    const float* __restrict__ p_ws, float* __restrict__ ext)
{
    int e = blockIdx.x * 256 + threadIdx.x;
    if (e < SEQ * 64) {
        int s = e >> 6, b = e & 63;
        float val = (1.f - p_ws[b]) * attn[e] * (mask[e] ? 1.f : 0.f);
        ext[(size_t)b * EXT + V + s] = val;
    }
}

// ---------------------------------------------------------------------------
extern "C" void kernel_launch(void* const* d_in, const int* in_sizes, int n_in,
                              void* d_out, int out_size, void* d_ws, size_t ws_size,
                              hipStream_t stream)
{
    (void)in_sizes; (void)n_in; (void)out_size; (void)ws_size;
    const float* x      = (const float*)d_in[0];
    const float* enc    = (const float*)d_in[1];
    const int*   mask   = (const int*)  d_in[2];
    const float* h0     = (const float*)d_in[3];
    const float* W_ih   = (const float*)d_in[4];
    const float* W_hh   = (const float*)d_in[5];
    const float* b_ih   = (const float*)d_in[6];
    const float* b_hh   = (const float*)d_in[7];
    const float* outW   = (const float*)d_in[8];
    const float* outb   = (const float*)d_in[9];
    const float* v      = (const float*)d_in[10];
    const float* Wh     = (const float*)d_in[11];
    const float* Ws     = (const float*)d_in[12];
    const float* b_attn = (const float*)d_in[13];
    const float* pWh    = (const float*)d_in[14];
    const float* pWs    = (const float*)d_in[15];
    const float* pWx    = (const float*)d_in[16];
    const float* pWx_b  = (const float*)d_in[17];

    float* out        = (float*)d_out;
    float* out_ext    = out;                           // 64 x 50400
    float* out_hidden = out + (size_t)64 * EXT;        // 64 x 512
    float* out_p      = out_hidden + 64 * H;           // 64
    float* out_attn   = out_p + 64;                    // 400 x 64

    float* ws      = (float*)d_ws;
    float* ws_x2   = ws;                               // 64*512
    float* ws_pd   = ws_x2 + 64 * H;                   // 64
    float* ws_part = ws_pd + 64;                       // 4*400*64
    float* ws_ctx  = ws_part + 4 * SEQ * 64;           // 64*512
    float* ws_p    = ws_ctx + 64 * H;                  // 64
    unsigned short* ws_whT = (unsigned short*)(ws_p + 64);  // 512*512 bf16 (512 KB)

    k0_transpose<<<dim3(8, 8), 256, 0, stream>>>(Wh, ws_whT);
    k1_gru<<<128, 256, 0, stream>>>(x, h0, W_ih, W_hh, b_ih, b_hh, out_hidden);
    k2_post<<<64, 512, 0, stream>>>(out_hidden, Ws, b_attn, x, pWs, pWx, pWx_b,
                                    ws_x2, ws_pd);
    k3_scores<<<dim3(SEQ, 4), 256, 0, stream>>>(enc, ws_whT, ws_x2, v, ws_part);
    k4_softmax<<<64, 512, 0, stream>>>(ws_part, out_attn);
    k5_context<<<dim3(64, 4), 128, 0, stream>>>(enc, out_attn, ws_ctx);
    k5b_p<<<64, 64, 0, stream>>>(ws_ctx, pWh, ws_pd, out_p, ws_p);
    k6_vocab<<<(V + 63) / 64, 256, 0, stream>>>(out_hidden, ws_ctx, outW, outb,
                                                ws_p, out_ext);
    k7_oov<<<(SEQ * 64 + 255) / 256, 256, 0, stream>>>(out_attn, mask, ws_p, out_ext);
}

// Round 4
// 519.974 us; speedup vs baseline: 2.3695x; 1.0708x over previous
//
#include <hip/hip_runtime.h>
#include <cmath>

#define H    512
#define H2   1024
#define V    50000
#define SEQ  400
#define EXT  (V + SEQ)   // 50400

typedef __attribute__((ext_vector_type(8))) short short8;
typedef __attribute__((ext_vector_type(4))) float floatx4;

// raw barrier: LDS visibility only; leaves vmcnt outstanding across the
// barrier (prefetch loads stay in flight -- the m97 stall workaround).
#define LDS_BARRIER() asm volatile("s_waitcnt lgkmcnt(0)\n\ts_barrier" ::: "memory")

__device__ __forceinline__ unsigned int bfpack2(float lo, float hi) {
    unsigned int a = __float_as_uint(lo) + 0x8000u;   // round-half-up
    unsigned int b = __float_as_uint(hi) + 0x8000u;
    return __builtin_amdgcn_perm(b, a, 0x07060302);   // {hi.b3,hi.b2,lo.b3,lo.b2}
}
__device__ __forceinline__ uint4 pack8(float4 a, float4 b) {
    uint4 r;
    r.x = bfpack2(a.x, a.y);
    r.y = bfpack2(a.z, a.w);
    r.z = bfpack2(b.x, b.y);
    r.w = bfpack2(b.z, b.w);
    return r;
}
__device__ __forceinline__ float4 ld4(const float* p) { return *(const float4*)p; }

// ---------------------------------------------------------------------------
// K0: WhT/WsT[n][k] = bf16(W[k][n]).  grid (8,8,2): z selects Wh vs Ws.
// ---------------------------------------------------------------------------
__global__ __launch_bounds__(256) void k0_transpose(
    const float* __restrict__ Wh, const float* __restrict__ Ws,
    unsigned short* __restrict__ WhT, unsigned short* __restrict__ WsT)
{
    __shared__ float T[64][65];
    const float* src = blockIdx.z ? Ws : Wh;
    unsigned short* dst = blockIdx.z ? WsT : WhT;
    const int k0 = blockIdx.x * 64, n0 = blockIdx.y * 64;
    const int tid = threadIdx.x;
    #pragma unroll
    for (int i = 0; i < 16; ++i) {
        int e = i * 256 + tid;
        int r = e >> 6, c = e & 63;
        T[r][c] = src[(size_t)(k0 + r) * H + n0 + c];
    }
    __syncthreads();
    #pragma unroll
    for (int i = 0; i < 16; ++i) {
        int e = i * 256 + tid;
        int nn = e >> 6, kk = e & 63;
        unsigned int u = __float_as_uint(T[kk][nn]) + 0x8000u;
        dst[(size_t)(n0 + nn) * H + k0 + kk] = (unsigned short)(u >> 16);
    }
}

// ---------------------------------------------------------------------------
// K1 v2 (MFMA): GRU step.  grid 8 blocks (64 j-columns each), 256 thr.
// 6 gate GEMM-tiles (W_ih/W_hh x r,z,n) share the x / h0 A-tiles.
// ---------------------------------------------------------------------------
__global__ __launch_bounds__(256) void k1_gru(
    const float* __restrict__ x, const float* __restrict__ h0,
    const float* __restrict__ W_ih, const float* __restrict__ W_hh,
    const float* __restrict__ b_ih, const float* __restrict__ b_hh,
    float* __restrict__ h_out)
{
    __shared__ uint4 Ax[512];      // x:  64 b x 8 kg
    __shared__ uint4 Ah[512];      // h0
    __shared__ uint4 Bg[6][512];   // 6 gate tiles, 64 n x 8 kg
    const int tid  = threadIdx.x;
    const int wave = tid >> 6, lane = tid & 63;
    const int lrow = lane & 15, q = lane >> 4;
    const int J0   = blockIdx.x * 64;

    floatx4 acc[6][4];
    #pragma unroll
    for (int g = 0; g < 6; ++g)
        #pragma unroll
        for (int mt = 0; mt < 4; ++mt) acc[g][mt] = (floatx4){0.f, 0.f, 0.f, 0.f};

    for (int kc = 0; kc < H; kc += 64) {
        __syncthreads();
        #pragma unroll
        for (int c = 0; c < 2; ++c) {
            int idx = c * 256 + tid;
            int m = idx >> 3, j2 = idx & 7, k8 = j2 ^ (m & 7);
            const float* sx = x  + m * H + kc + k8 * 8;
            const float* sh = h0 + m * H + kc + k8 * 8;
            Ax[idx] = pack8(ld4(sx), ld4(sx + 4));
            Ah[idx] = pack8(ld4(sh), ld4(sh + 4));
        }
        #pragma unroll
        for (int g = 0; g < 6; ++g) {
            const float* Wb = (g < 3) ? W_ih : W_hh;
            const int go = (g % 3) * H;
            #pragma unroll
            for (int c = 0; c < 2; ++c) {
                int idx = c * 256 + tid;
                int n = idx >> 3, j2 = idx & 7, k8 = j2 ^ (n & 7);
                const float* sw = Wb + (size_t)(go + J0 + n) * H + kc + k8 * 8;
                Bg[g][idx] = pack8(ld4(sw), ld4(sw + 4));
            }
        }
        __syncthreads();
        #pragma unroll
        for (int kk8 = 0; kk8 < 8; kk8 += 4) {
            const int k8 = kk8 + q;
            short8 ax[4], ah[4];
            #pragma unroll
            for (int mt = 0; mt < 4; ++mt) {
                int m = mt * 16 + lrow;
                ax[mt] = *(const short8*)&Ax[m * 8 + (k8 ^ (m & 7))];
                ah[mt] = *(const short8*)&Ah[m * 8 + (k8 ^ (m & 7))];
            }
            const int n = wave * 16 + lrow;
            const int gidx = n * 8 + (k8 ^ (n & 7));
            #pragma unroll
            for (int g = 0; g < 6; ++g) {
                short8 bb = *(const short8*)&Bg[g][gidx];
                #pragma unroll
                for (int mt = 0; mt < 4; ++mt)
                    acc[g][mt] = __builtin_amdgcn_mfma_f32_16x16x32_bf16(
                        (g < 3) ? ax[mt] : ah[mt], bb, acc[g][mt], 0, 0, 0);
            }
        }
    }
    const int j = J0 + wave * 16 + lrow;
    const float bir = b_ih[j], biz = b_ih[H + j], bin = b_ih[2 * H + j];
    const float bhr = b_hh[j], bhz = b_hh[H + j], bhn = b_hh[2 * H + j];
    #pragma unroll
    for (int mt = 0; mt < 4; ++mt) {
        #pragma unroll
        for (int r = 0; r < 4; ++r) {
            const int bb = mt * 16 + q * 4 + r;
            float rg = 1.f / (1.f + expf(-(acc[0][mt][r] + bir + acc[3][mt][r] + bhr)));
            float zg = 1.f / (1.f + expf(-(acc[1][mt][r] + biz + acc[4][mt][r] + bhz)));
            float ng = tanhf(acc[2][mt][r] + bin + rg * (acc[5][mt][r] + bhn));
            float h0v = h0[bb * H + j];
            h_out[bb * H + j] = (1.f - zg) * ng + zg * h0v;
        }
    }
}

// ---------------------------------------------------------------------------
// K2 v2 (MFMA): x2 = h @ Ws + b_attn.  grid 8 (64 n each).  B = WsT bf16.
// ---------------------------------------------------------------------------
__global__ __launch_bounds__(256) void k2_x2(
    const float* __restrict__ h, const unsigned short* __restrict__ WsT,
    const float* __restrict__ b_attn, float* __restrict__ x2)
{
    __shared__ uint4 Ag[512];
    __shared__ uint4 Bgg[512];
    const int tid  = threadIdx.x;
    const int wave = tid >> 6, lane = tid & 63;
    const int lrow = lane & 15, q = lane >> 4;
    const int n0   = blockIdx.x * 64;

    floatx4 acc[4];
    #pragma unroll
    for (int mt = 0; mt < 4; ++mt) acc[mt] = (floatx4){0.f, 0.f, 0.f, 0.f};

    for (int kc = 0; kc < H; kc += 64) {
        __syncthreads();
        #pragma unroll
        for (int c = 0; c < 2; ++c) {
            int idx = c * 256 + tid;
            int m = idx >> 3, j2 = idx & 7, k8 = j2 ^ (m & 7);
            const float* sh = h + m * H + kc + k8 * 8;
            Ag[idx] = pack8(ld4(sh), ld4(sh + 4));
            int n = m, k8b = j2 ^ (n & 7);
            Bgg[idx] = *(const uint4*)(WsT + (size_t)(n0 + n) * H + kc + k8b * 8);
        }
        __syncthreads();
        #pragma unroll
        for (int kk8 = 0; kk8 < 8; kk8 += 4) {
            const int k8 = kk8 + q;
            const int n = wave * 16 + lrow;
            short8 bb = *(const short8*)&Bgg[n * 8 + (k8 ^ (n & 7))];
            #pragma unroll
            for (int mt = 0; mt < 4; ++mt) {
                int m = mt * 16 + lrow;
                short8 a = *(const short8*)&Ag[m * 8 + (k8 ^ (m & 7))];
                acc[mt] = __builtin_amdgcn_mfma_f32_16x16x32_bf16(a, bb, acc[mt], 0, 0, 0);
            }
        }
    }
    const int n = n0 + wave * 16 + lrow;
    const float ba = b_attn[n];
    #pragma unroll
    for (int mt = 0; mt < 4; ++mt)
        #pragma unroll
        for (int r = 0; r < 4; ++r) {
            const int bb = mt * 16 + q * 4 + r;
            x2[bb * H + n] = acc[mt][r] + ba;
        }
}

// ---------------------------------------------------------------------------
// K3 v4: MFMA + double-buffered LDS + register prefetch + raw LDS barrier.
// Global loads for chunk kc+1 stay in flight across the barrier (vmcnt not
// drained); consumer waitcnt lands at next iter's pack8.
// ---------------------------------------------------------------------------
__global__ __launch_bounds__(256) void k3_scores(
    const float* __restrict__ enc, const unsigned short* __restrict__ WhT,
    const float* __restrict__ x2, const float* __restrict__ v,
    float* __restrict__ part)
{
    __shared__ uint4 AsG[2][512];
    __shared__ uint4 BsG[2][1024];
    __shared__ float red[256];
    const int s   = blockIdx.x;
    const int nc  = blockIdx.y;
    const int n0  = nc * 128;
    const int tid  = threadIdx.x;
    const int wave = tid >> 6, lane = tid & 63;
    const int lrow = lane & 15, q = lane >> 4;

    const float* Abase = enc + (size_t)s * 64 * H;

    float4 arA[2][2];
    uint4  arB[4];
    #pragma unroll
    for (int c = 0; c < 2; ++c) {
        int idx = c * 256 + tid;
        int m = idx >> 3, k8 = (idx & 7) ^ (m & 7);
        const float* sa = Abase + m * H + k8 * 8;
        arA[c][0] = ld4(sa); arA[c][1] = ld4(sa + 4);
    }
    #pragma unroll
    for (int c = 0; c < 4; ++c) {
        int idx = c * 256 + tid;
        int n = idx >> 3, k8 = (idx & 7) ^ (n & 7);
        arB[c] = *(const uint4*)(WhT + (size_t)(n0 + n) * H + k8 * 8);
    }

    floatx4 acc[4][2];
    #pragma unroll
    for (int mt = 0; mt < 4; ++mt)
        #pragma unroll
        for (int nt = 0; nt < 2; ++nt) acc[mt][nt] = (floatx4){0.f, 0.f, 0.f, 0.f};

    for (int kc = 0; kc < 8; ++kc) {
        const int buf = kc & 1;
        #pragma unroll
        for (int c = 0; c < 2; ++c)
            AsG[buf][c * 256 + tid] = pack8(arA[c][0], arA[c][1]);
        #pragma unroll
        for (int c = 0; c < 4; ++c)
            BsG[buf][c * 256 + tid] = arB[c];
        if (kc < 7) {
            const int ko = (kc + 1) * 64;
            #pragma unroll
            for (int c = 0; c < 2; ++c) {
                int idx = c * 256 + tid;
                int m = idx >> 3, k8 = (idx & 7) ^ (m & 7);
                const float* sa = Abase + m * H + ko + k8 * 8;
                arA[c][0] = ld4(sa); arA[c][1] = ld4(sa + 4);
            }
            #pragma unroll
            for (int c = 0; c < 4; ++c) {
                int idx = c * 256 + tid;
                int n = idx >> 3, k8 = (idx & 7) ^ (n & 7);
                arB[c] = *(const uint4*)(WhT + (size_t)(n0 + n) * H + ko + k8 * 8);
            }
        }
        LDS_BARRIER();
        #pragma unroll
        for (int kk8 = 0; kk8 < 8; kk8 += 4) {
            const int k8 = kk8 + q;
            short8 a[4], b[2];
            #pragma unroll
            for (int mt = 0; mt < 4; ++mt) {
                int m = mt * 16 + lrow;
                a[mt] = *(const short8*)&AsG[buf][m * 8 + (k8 ^ (m & 7))];
            }
            #pragma unroll
            for (int nt = 0; nt < 2; ++nt) {
                int n = wave * 32 + nt * 16 + lrow;
                b[nt] = *(const short8*)&BsG[buf][n * 8 + (k8 ^ (n & 7))];
            }
            #pragma unroll
            for (int mt = 0; mt < 4; ++mt)
                #pragma unroll
                for (int nt = 0; nt < 2; ++nt)
                    acc[mt][nt] = __builtin_amdgcn_mfma_f32_16x16x32_bf16(
                        a[mt], b[nt], acc[mt][nt], 0, 0, 0);
        }
    }
    // fused epilogue: tanh(acc + x2)*v, reduce over wave's 32 n
    float val[4][4];
    #pragma unroll
    for (int mt = 0; mt < 4; ++mt) {
        #pragma unroll
        for (int r = 0; r < 4; ++r) {
            const int bb = mt * 16 + q * 4 + r;
            float sum = 0.f;
            #pragma unroll
            for (int nt = 0; nt < 2; ++nt) {
                const int n = n0 + wave * 32 + nt * 16 + lrow;
                sum += tanhf(acc[mt][nt][r] + x2[bb * H + n]) * v[n];
            }
            #pragma unroll
            for (int off = 8; off > 0; off >>= 1) sum += __shfl_down(sum, off, 16);
            val[mt][r] = sum;
        }
    }
    __syncthreads();
    if (lrow == 0) {
        #pragma unroll
        for (int mt = 0; mt < 4; ++mt)
            #pragma unroll
            for (int r = 0; r < 4; ++r)
                red[wave * 64 + mt * 16 + q * 4 + r] = val[mt][r];
    }
    __syncthreads();
    if (tid < 64) {
        float sc = red[tid] + red[64 + tid] + red[128 + tid] + red[192 + tid];
        part[((size_t)nc * SEQ + s) * 64 + tid] = sc;
    }
}

// ---------------------------------------------------------------------------
// K4: softmax over s per batch.  (unchanged)
// ---------------------------------------------------------------------------
__global__ __launch_bounds__(512) void k4_softmax(
    const float* __restrict__ part, float* __restrict__ attn_out)
{
    const int b = blockIdx.x;
    const int t = threadIdx.x;
    __shared__ float red[8];
    __shared__ float smax, ssum;
    float myv = 0.f, val = -1e30f;
    if (t < SEQ) {
        myv = part[((size_t)0 * SEQ + t) * 64 + b]
            + part[((size_t)1 * SEQ + t) * 64 + b]
            + part[((size_t)2 * SEQ + t) * 64 + b]
            + part[((size_t)3 * SEQ + t) * 64 + b];
        val = myv;
    }
    float m = val;
    #pragma unroll
    for (int off = 32; off > 0; off >>= 1) m = fmaxf(m, __shfl_down(m, off, 64));
    if ((t & 63) == 0) red[t >> 6] = m;
    __syncthreads();
    if (t == 0) {
        float mm = red[0];
        #pragma unroll
        for (int w = 1; w < 8; ++w) mm = fmaxf(mm, red[w]);
        smax = mm;
    }
    __syncthreads();
    float e = (t < SEQ) ? expf(myv - smax) : 0.f;
    float ssv = e;
    #pragma unroll
    for (int off = 32; off > 0; off >>= 1) ssv += __shfl_down(ssv, off, 64);
    if ((t & 63) == 0) red[t >> 6] = ssv;
    __syncthreads();
    if (t == 0) {
        float ss = 0.f;
        #pragma unroll
        for (int w = 0; w < 8; ++w) ss += red[w];
        ssum = ss;
    }
    __syncthreads();
    if (t < SEQ) attn_out[t * 64 + b] = e / ssum;
}

// ---------------------------------------------------------------------------
// K5 v2: context partials.  grid (64 b, 4 hc, 4 sg) -> 4x the waves of v1
// (latency-bound fix); each block sums 100 s into ctxp[sg][b][h].
// ---------------------------------------------------------------------------
__global__ __launch_bounds__(128) void k5_context(
    const float* __restrict__ enc, const float* __restrict__ attn,
    float* __restrict__ ctxp)
{
    const int b  = blockIdx.x;
    const int hc = blockIdx.y;
    const int sg = blockIdx.z;
    const int t  = threadIdx.x;
    __shared__ float a_s[100];
    if (t < 100) a_s[t] = attn[(sg * 100 + t) * 64 + b];
    __syncthreads();
    const int hh = hc * 128 + t;
    const float* p = enc + ((size_t)(sg * 100) * 64 + b) * H + hh;
    float a0 = 0.f, a1 = 0.f;
    #pragma unroll 5
    for (int i = 0; i < 100; i += 2) {
        a0 += a_s[i]     * p[0];
        a1 += a_s[i + 1] * p[(size_t)64 * H];
        p += (size_t)128 * H;
    }
    ctxp[((size_t)sg * 64 + b) * H + hh] = a0 + a1;
}

// ---------------------------------------------------------------------------
// K5b v2: reduce ctx partials; p[b] = sigmoid(ctx.pWh + h.pWs + x.pWx + b).
// ---------------------------------------------------------------------------
__global__ __launch_bounds__(512) void k5b_p(
    const float* __restrict__ ctxp, const float* __restrict__ pWh,
    const float* __restrict__ hdec, const float* __restrict__ pWs,
    const float* __restrict__ x, const float* __restrict__ pWx,
    const float* __restrict__ pWx_b,
    float* __restrict__ ctx, float* __restrict__ p_out, float* __restrict__ p_ws)
{
    const int b = blockIdx.x;
    const int t = threadIdx.x;
    __shared__ float rbuf[8];
    float c = ctxp[((size_t)0 * 64 + b) * H + t]
            + ctxp[((size_t)1 * 64 + b) * H + t]
            + ctxp[((size_t)2 * 64 + b) * H + t]
            + ctxp[((size_t)3 * 64 + b) * H + t];
    ctx[b * H + t] = c;
    float term = c * pWh[t] + hdec[b * H + t] * pWs[t] + x[b * H + t] * pWx[t];
    #pragma unroll
    for (int off = 32; off > 0; off >>= 1) term += __shfl_down(term, off, 64);
    if ((t & 63) == 0) rbuf[t >> 6] = term;
    __syncthreads();
    if (t == 0) {
        float ssv = pWx_b[0];
        #pragma unroll
        for (int w = 0; w < 8; ++w) ssv += rbuf[w];
        float pv = 1.f / (1.f + expf(-ssv));
        p_out[b] = pv;
        p_ws[b]  = pv;
    }
}

// ---------------------------------------------------------------------------
// K6 v4: MFMA + dbuf + register prefetch + raw LDS barrier.  HBM floor
// (out_W 205 MB) = 33 us; prefetch keeps the stream in flight across the
// per-chunk barrier.
// ---------------------------------------------------------------------------
__global__ __launch_bounds__(256) void k6_vocab(
    const float* __restrict__ h, const float* __restrict__ ctx,
    const float* __restrict__ outW, const float* __restrict__ outb,
    const float* __restrict__ p_ws, float* __restrict__ ext)
{
    __shared__ uint4 AsG[2][512];
    __shared__ uint4 BsG[2][512];
    __shared__ float p_l[64];
    const int tid  = threadIdx.x;
    const int wave = tid >> 6, lane = tid & 63;
    const int lrow = lane & 15, q = lane >> 4;
    const int v0   = blockIdx.x * 64;

    if (tid < 64) p_l[tid] = p_ws[tid];

    float4 arA[2][2], arB[2][2];
    {
        const float* Ab = h;   // kc=0 chunk source
        #pragma unroll
        for (int c = 0; c < 2; ++c) {
            int idx = c * 256 + tid;
            int m = idx >> 3, k8 = (idx & 7) ^ (m & 7);
            const float* sa = Ab + m * H + k8 * 8;
            arA[c][0] = ld4(sa); arA[c][1] = ld4(sa + 4);
            int n = m, k8b = (idx & 7) ^ (n & 7);
            int vr = v0 + n; if (vr >= V) vr = V - 1;
            const float* sb = outW + (size_t)vr * H2 + k8b * 8;
            arB[c][0] = ld4(sb); arB[c][1] = ld4(sb + 4);
        }
    }

    floatx4 acc[4];
    #pragma unroll
    for (int mt = 0; mt < 4; ++mt) acc[mt] = (floatx4){0.f, 0.f, 0.f, 0.f};

    for (int kc = 0; kc < 16; ++kc) {
        const int buf = kc & 1;
        #pragma unroll
        for (int c = 0; c < 2; ++c) {
            AsG[buf][c * 256 + tid] = pack8(arA[c][0], arA[c][1]);
            BsG[buf][c * 256 + tid] = pack8(arB[c][0], arB[c][1]);
        }
        if (kc < 15) {
            const int ko = (kc + 1) * 64;
            const float* Ab = (ko < H) ? (h + ko) : (ctx + (ko - H));
            #pragma unroll
            for (int c = 0; c < 2; ++c) {
                int idx = c * 256 + tid;
                int m = idx >> 3, k8 = (idx & 7) ^ (m & 7);
                const float* sa = Ab + m * H + k8 * 8;
                arA[c][0] = ld4(sa); arA[c][1] = ld4(sa + 4);
                int n = m, k8b = (idx & 7) ^ (n & 7);
                int vr = v0 + n; if (vr >= V) vr = V - 1;
                const float* sb = outW + (size_t)vr * H2 + ko + k8b * 8;
                arB[c][0] = ld4(sb); arB[c][1] = ld4(sb + 4);
            }
        }
        LDS_BARRIER();
        #pragma unroll
        for (int kk8 = 0; kk8 < 8; kk8 += 4) {
            const int k8 = kk8 + q;
            const int n = wave * 16 + lrow;
            short8 b = *(const short8*)&BsG[buf][n * 8 + (k8 ^ (n & 7))];
            #pragma unroll
            for (int mt = 0; mt < 4; ++mt) {
                int m = mt * 16 + lrow;
                short8 a = *(const short8*)&AsG[buf][m * 8 + (k8 ^ (m & 7))];
                acc[mt] = __builtin_amdgcn_mfma_f32_16x16x32_bf16(a, b, acc[mt], 0, 0, 0);
            }
        }
    }
    const int n = v0 + wave * 16 + lrow;
    if (n < V) {
        const float ob = outb[n];
        #pragma unroll
        for (int mt = 0; mt < 4; ++mt) {
            #pragma unroll
            for (int r = 0; r < 4; ++r) {
                const int bb = mt * 16 + q * 4 + r;
                float zz = acc[mt][r] + ob;
                float sv = (zz > 0.f) ? 1.0507009873554805f * zz
                                      : 1.7580993408473766f * (expf(zz) - 1.f);
                ext[(size_t)bb * EXT + n] = p_l[bb] * sv;
            }
        }
    }
}

// ---------------------------------------------------------------------------
// K7: oov tail.  (unchanged)
// ---------------------------------------------------------------------------
__global__ __launch_bounds__(256) void k7_oov(
    const float* __restrict__ attn, const int* __restrict__ mask,
    const float* __restrict__ p_ws, float* __restrict__ ext)
{
    int e = blockIdx.x * 256 + threadIdx.x;
    if (e < SEQ * 64) {
        int s = e >> 6, b = e & 63;
        float val = (1.f - p_ws[b]) * attn[e] * (mask[e] ? 1.f : 0.f);
        ext[(size_t)b * EXT + V + s] = val;
    }
}

// ---------------------------------------------------------------------------
extern "C" void kernel_launch(void* const* d_in, const int* in_sizes, int n_in,
                              void* d_out, int out_size, void* d_ws, size_t ws_size,
                              hipStream_t stream)
{
    (void)in_sizes; (void)n_in; (void)out_size; (void)ws_size;
    const float* x      = (const float*)d_in[0];
    const float* enc    = (const float*)d_in[1];
    const int*   mask   = (const int*)  d_in[2];
    const float* h0     = (const float*)d_in[3];
    const float* W_ih   = (const float*)d_in[4];
    const float* W_hh   = (const float*)d_in[5];
    const float* b_ih   = (const float*)d_in[6];
    const float* b_hh   = (const float*)d_in[7];
    const float* outW   = (const float*)d_in[8];
    const float* outb   = (const float*)d_in[9];
    const float* v      = (const float*)d_in[10];
    const float* Wh     = (const float*)d_in[11];
    const float* Ws     = (const float*)d_in[12];
    const float* b_attn = (const float*)d_in[13];
    const float* pWh    = (const float*)d_in[14];
    const float* pWs    = (const float*)d_in[15];
    const float* pWx    = (const float*)d_in[16];
    const float* pWx_b  = (const float*)d_in[17];

    float* out        = (float*)d_out;
    float* out_ext    = out;                           // 64 x 50400
    float* out_hidden = out + (size_t)64 * EXT;        // 64 x 512
    float* out_p      = out_hidden + 64 * H;           // 64
    float* out_attn   = out_p + 64;                    // 400 x 64

    float* ws       = (float*)d_ws;
    float* ws_x2    = ws;                              // 64*512
    float* ws_part  = ws_x2 + 64 * H;                  // 4*400*64
    float* ws_ctxp  = ws_part + 4 * SEQ * 64;          // 4*64*512
    float* ws_ctx   = ws_ctxp + 4 * 64 * H;            // 64*512
    float* ws_p     = ws_ctx + 64 * H;                 // 64
    unsigned short* ws_whT = (unsigned short*)(ws_p + 64);      // 512*512 bf16
    unsigned short* ws_wsT = ws_whT + (size_t)H * H;            // 512*512 bf16

    k0_transpose<<<dim3(8, 8, 2), 256, 0, stream>>>(Wh, Ws, ws_whT, ws_wsT);
    k1_gru<<<8, 256, 0, stream>>>(x, h0, W_ih, W_hh, b_ih, b_hh, out_hidden);
    k2_x2<<<8, 256, 0, stream>>>(out_hidden, ws_wsT, b_attn, ws_x2);
    k3_scores<<<dim3(SEQ, 4), 256, 0, stream>>>(enc, ws_whT, ws_x2, v, ws_part);
    k4_softmax<<<64, 512, 0, stream>>>(ws_part, out_attn);
    k5_context<<<dim3(64, 4, 4), 128, 0, stream>>>(enc, out_attn, ws_ctxp);
    k5b_p<<<64, 512, 0, stream>>>(ws_ctxp, pWh, out_hidden, pWs, x, pWx, pWx_b,
                                  ws_ctx, out_p, ws_p);
    k6_vocab<<<(V + 63) / 64, 256, 0, stream>>>(out_hidden, ws_ctx, outW, outb,
                                                ws_p, out_ext);
    k7_oov<<<(SEQ * 64 + 255) / 256, 256, 0, stream>>>(out_attn, mask, ws_p, out_ext);
}

// Round 5
// 463.849 us; speedup vs baseline: 2.6562x; 1.1210x over previous
//
#include <hip/hip_runtime.h>
#include <cmath>

#define H    512
#define H2   1024
#define V    50000
#define SEQ  400
#define EXT  (V + SEQ)   // 50400

typedef __attribute__((ext_vector_type(8))) short short8;
typedef __attribute__((ext_vector_type(4))) float floatx4;

__device__ __forceinline__ unsigned int bfpack2(float lo, float hi) {
    unsigned int a = __float_as_uint(lo) + 0x8000u;   // round-half-up
    unsigned int b = __float_as_uint(hi) + 0x8000u;
    return __builtin_amdgcn_perm(b, a, 0x07060302);   // {hi.b3,hi.b2,lo.b3,lo.b2}
}
__device__ __forceinline__ uint4 pack8(float4 a, float4 b) {
    uint4 r;
    r.x = bfpack2(a.x, a.y);
    r.y = bfpack2(a.z, a.w);
    r.z = bfpack2(b.x, b.y);
    r.w = bfpack2(b.z, b.w);
    return r;
}
__device__ __forceinline__ float4 ld4(const float* p) { return *(const float4*)p; }

// ---------------------------------------------------------------------------
// K0: WhT/WsT[n][k] = bf16(W[k][n]).  grid (8,8,2): z selects Wh vs Ws.
// ---------------------------------------------------------------------------
__global__ __launch_bounds__(256) void k0_transpose(
    const float* __restrict__ Wh, const float* __restrict__ Ws,
    unsigned short* __restrict__ WhT, unsigned short* __restrict__ WsT)
{
    __shared__ float T[64][65];
    const float* src = blockIdx.z ? Ws : Wh;
    unsigned short* dst = blockIdx.z ? WsT : WhT;
    const int k0 = blockIdx.x * 64, n0 = blockIdx.y * 64;
    const int tid = threadIdx.x;
    #pragma unroll
    for (int i = 0; i < 16; ++i) {
        int e = i * 256 + tid;
        int r = e >> 6, c = e & 63;
        T[r][c] = src[(size_t)(k0 + r) * H + n0 + c];
    }
    __syncthreads();
    #pragma unroll
    for (int i = 0; i < 16; ++i) {
        int e = i * 256 + tid;
        int nn = e >> 6, kk = e & 63;
        unsigned int u = __float_as_uint(T[kk][nn]) + 0x8000u;
        dst[(size_t)(n0 + nn) * H + k0 + kk] = (unsigned short)(u >> 16);
    }
}

// ---------------------------------------------------------------------------
// K1 v3 (MFMA, K-split): GRU gate partials.  grid (8 j-blocks, 8 k-slices)
// = 64 blocks; each block does ONE 64-wide K chunk (no K loop, 1 barrier).
// Partials gacc[g][ks][b][j] fp32; k1b reduces and applies gate math.
// ---------------------------------------------------------------------------
__global__ __launch_bounds__(256) void k1_gru_part(
    const float* __restrict__ x, const float* __restrict__ h0,
    const float* __restrict__ W_ih, const float* __restrict__ W_hh,
    float* __restrict__ gacc)
{
    __shared__ uint4 Ax[512];      // x:  64 b x 8 kg
    __shared__ uint4 Ah[512];      // h0
    __shared__ uint4 Bg[6][512];   // 6 gate tiles, 64 n x 8 kg
    const int tid  = threadIdx.x;
    const int wave = tid >> 6, lane = tid & 63;
    const int lrow = lane & 15, q = lane >> 4;
    const int J0   = blockIdx.x * 64;
    const int ks   = blockIdx.y;
    const int kc   = ks * 64;

    #pragma unroll
    for (int c = 0; c < 2; ++c) {
        int idx = c * 256 + tid;
        int m = idx >> 3, j2 = idx & 7, k8 = j2 ^ (m & 7);
        const float* sx = x  + m * H + kc + k8 * 8;
        const float* sh = h0 + m * H + kc + k8 * 8;
        Ax[idx] = pack8(ld4(sx), ld4(sx + 4));
        Ah[idx] = pack8(ld4(sh), ld4(sh + 4));
    }
    #pragma unroll
    for (int g = 0; g < 6; ++g) {
        const float* Wb = (g < 3) ? W_ih : W_hh;
        const int go = (g % 3) * H;
        #pragma unroll
        for (int c = 0; c < 2; ++c) {
            int idx = c * 256 + tid;
            int n = idx >> 3, j2 = idx & 7, k8 = j2 ^ (n & 7);
            const float* sw = Wb + (size_t)(go + J0 + n) * H + kc + k8 * 8;
            Bg[g][idx] = pack8(ld4(sw), ld4(sw + 4));
        }
    }
    __syncthreads();

    floatx4 acc[6];
    #pragma unroll
    for (int g = 0; g < 6; ++g) acc[g] = (floatx4){0.f, 0.f, 0.f, 0.f};
    // NOTE: each wave covers n=16 j-cols; mt covers all 64 b rows via 4 tiles.
    floatx4 accm[6][4];
    #pragma unroll
    for (int g = 0; g < 6; ++g)
        #pragma unroll
        for (int mt = 0; mt < 4; ++mt) accm[g][mt] = (floatx4){0.f, 0.f, 0.f, 0.f};

    #pragma unroll
    for (int kk8 = 0; kk8 < 8; kk8 += 4) {
        const int k8 = kk8 + q;
        short8 ax[4], ah[4];
        #pragma unroll
        for (int mt = 0; mt < 4; ++mt) {
            int m = mt * 16 + lrow;
            ax[mt] = *(const short8*)&Ax[m * 8 + (k8 ^ (m & 7))];
            ah[mt] = *(const short8*)&Ah[m * 8 + (k8 ^ (m & 7))];
        }
        const int n = wave * 16 + lrow;
        const int gidx = n * 8 + (k8 ^ (n & 7));
        #pragma unroll
        for (int g = 0; g < 6; ++g) {
            short8 bb = *(const short8*)&Bg[g][gidx];
            #pragma unroll
            for (int mt = 0; mt < 4; ++mt)
                accm[g][mt] = __builtin_amdgcn_mfma_f32_16x16x32_bf16(
                    (g < 3) ? ax[mt] : ah[mt], bb, accm[g][mt], 0, 0, 0);
        }
    }
    const int j = J0 + wave * 16 + lrow;
    #pragma unroll
    for (int g = 0; g < 6; ++g)
        #pragma unroll
        for (int mt = 0; mt < 4; ++mt)
            #pragma unroll
            for (int r = 0; r < 4; ++r) {
                const int bb = mt * 16 + q * 4 + r;
                gacc[(((size_t)g * 8 + ks) * 64 + bb) * H + j] = accm[g][mt][r];
            }
}

// ---------------------------------------------------------------------------
// K1b: reduce k-slices, apply GRU gate math.  grid 128 x 256 (one thr/(b,j)).
// ---------------------------------------------------------------------------
__global__ __launch_bounds__(256) void k1_gru_fin(
    const float* __restrict__ gacc, const float* __restrict__ h0,
    const float* __restrict__ b_ih, const float* __restrict__ b_hh,
    float* __restrict__ h_out)
{
    const int e = blockIdx.x * 256 + threadIdx.x;
    const int j = e & (H - 1);
    const int b = e >> 9;
    float gs[6];
    #pragma unroll
    for (int g = 0; g < 6; ++g) {
        float sum = 0.f;
        #pragma unroll
        for (int ks = 0; ks < 8; ++ks)
            sum += gacc[(((size_t)g * 8 + ks) * 64 + b) * H + j];
        gs[g] = sum;
    }
    float rg = 1.f / (1.f + expf(-(gs[0] + b_ih[j] + gs[3] + b_hh[j])));
    float zg = 1.f / (1.f + expf(-(gs[1] + b_ih[H + j] + gs[4] + b_hh[H + j])));
    float ng = tanhf(gs[2] + b_ih[2 * H + j] + rg * (gs[5] + b_hh[2 * H + j]));
    float h0v = h0[b * H + j];
    h_out[b * H + j] = (1.f - zg) * ng + zg * h0v;
}

// ---------------------------------------------------------------------------
// K2 (MFMA): x2 = h @ Ws + b_attn.  grid 8 (64 n each).  B = WsT bf16.
// ---------------------------------------------------------------------------
__global__ __launch_bounds__(256) void k2_x2(
    const float* __restrict__ h, const unsigned short* __restrict__ WsT,
    const float* __restrict__ b_attn, float* __restrict__ x2)
{
    __shared__ uint4 Ag[512];
    __shared__ uint4 Bgg[512];
    const int tid  = threadIdx.x;
    const int wave = tid >> 6, lane = tid & 63;
    const int lrow = lane & 15, q = lane >> 4;
    const int n0   = blockIdx.x * 64;

    floatx4 acc[4];
    #pragma unroll
    for (int mt = 0; mt < 4; ++mt) acc[mt] = (floatx4){0.f, 0.f, 0.f, 0.f};

    for (int kc = 0; kc < H; kc += 64) {
        __syncthreads();
        #pragma unroll
        for (int c = 0; c < 2; ++c) {
            int idx = c * 256 + tid;
            int m = idx >> 3, j2 = idx & 7, k8 = j2 ^ (m & 7);
            const float* sh = h + m * H + kc + k8 * 8;
            Ag[idx] = pack8(ld4(sh), ld4(sh + 4));
            Bgg[idx] = *(const uint4*)(WsT + (size_t)(n0 + m) * H + kc + k8 * 8);
        }
        __syncthreads();
        #pragma unroll
        for (int kk8 = 0; kk8 < 8; kk8 += 4) {
            const int k8 = kk8 + q;
            const int n = wave * 16 + lrow;
            short8 bb = *(const short8*)&Bgg[n * 8 + (k8 ^ (n & 7))];
            #pragma unroll
            for (int mt = 0; mt < 4; ++mt) {
                int m = mt * 16 + lrow;
                short8 a = *(const short8*)&Ag[m * 8 + (k8 ^ (m & 7))];
                acc[mt] = __builtin_amdgcn_mfma_f32_16x16x32_bf16(a, bb, acc[mt], 0, 0, 0);
            }
        }
    }
    const int n = n0 + wave * 16 + lrow;
    const float ba = b_attn[n];
    #pragma unroll
    for (int mt = 0; mt < 4; ++mt)
        #pragma unroll
        for (int r = 0; r < 4; ++r) {
            const int bb = mt * 16 + q * 4 + r;
            x2[bb * H + n] = acc[mt][r] + ba;
        }
}

// ---------------------------------------------------------------------------
// K3 v5: MFMA, single-buffered (revert of raw-barrier dbuf -- m99/m131-141:
// explicit pipelining on this structure is neutral/regressive; occupancy-level
// overlap does the job).  M=64 x N=128 x K=512 per block, grid (400, 4).
// ---------------------------------------------------------------------------
__global__ __launch_bounds__(256) void k3_scores(
    const float* __restrict__ enc, const unsigned short* __restrict__ WhT,
    const float* __restrict__ x2, const float* __restrict__ v,
    float* __restrict__ part)
{
    __shared__ uint4 AsG[512];    // 64 m  x 8 kg
    __shared__ uint4 BsG[1024];   // 128 n x 8 kg
    __shared__ float red[256];
    const int s   = blockIdx.x;
    const int nc  = blockIdx.y;
    const int n0  = nc * 128;
    const int tid  = threadIdx.x;
    const int wave = tid >> 6, lane = tid & 63;
    const int lrow = lane & 15, q = lane >> 4;

    floatx4 acc[4][2];
    #pragma unroll
    for (int mt = 0; mt < 4; ++mt)
        #pragma unroll
        for (int nt = 0; nt < 2; ++nt) acc[mt][nt] = (floatx4){0.f, 0.f, 0.f, 0.f};

    const float* Abase = enc + (size_t)s * 64 * H;
    for (int kc = 0; kc < H; kc += 64) {
        __syncthreads();
        #pragma unroll
        for (int c = 0; c < 2; ++c) {
            int idx = c * 256 + tid;
            int m = idx >> 3, k8 = (idx & 7) ^ (m & 7);
            const float* sa = Abase + m * H + kc + k8 * 8;
            AsG[idx] = pack8(ld4(sa), ld4(sa + 4));
        }
        #pragma unroll
        for (int c = 0; c < 4; ++c) {
            int idx = c * 256 + tid;
            int n = idx >> 3, k8 = (idx & 7) ^ (n & 7);
            BsG[idx] = *(const uint4*)(WhT + (size_t)(n0 + n) * H + kc + k8 * 8);
        }
        __syncthreads();
        #pragma unroll
        for (int kk8 = 0; kk8 < 8; kk8 += 4) {
            const int k8 = kk8 + q;
            short8 a[4], b[2];
            #pragma unroll
            for (int mt = 0; mt < 4; ++mt) {
                int m = mt * 16 + lrow;
                a[mt] = *(const short8*)&AsG[m * 8 + (k8 ^ (m & 7))];
            }
            #pragma unroll
            for (int nt = 0; nt < 2; ++nt) {
                int n = wave * 32 + nt * 16 + lrow;
                b[nt] = *(const short8*)&BsG[n * 8 + (k8 ^ (n & 7))];
            }
            #pragma unroll
            for (int mt = 0; mt < 4; ++mt)
                #pragma unroll
                for (int nt = 0; nt < 2; ++nt)
                    acc[mt][nt] = __builtin_amdgcn_mfma_f32_16x16x32_bf16(
                        a[mt], b[nt], acc[mt][nt], 0, 0, 0);
        }
    }
    float val[4][4];
    #pragma unroll
    for (int mt = 0; mt < 4; ++mt) {
        #pragma unroll
        for (int r = 0; r < 4; ++r) {
            const int bb = mt * 16 + q * 4 + r;
            float sum = 0.f;
            #pragma unroll
            for (int nt = 0; nt < 2; ++nt) {
                const int n = n0 + wave * 32 + nt * 16 + lrow;
                sum += tanhf(acc[mt][nt][r] + x2[bb * H + n]) * v[n];
            }
            #pragma unroll
            for (int off = 8; off > 0; off >>= 1) sum += __shfl_down(sum, off, 16);
            val[mt][r] = sum;
        }
    }
    __syncthreads();
    if (lrow == 0) {
        #pragma unroll
        for (int mt = 0; mt < 4; ++mt)
            #pragma unroll
            for (int r = 0; r < 4; ++r)
                red[wave * 64 + mt * 16 + q * 4 + r] = val[mt][r];
    }
    __syncthreads();
    if (tid < 64) {
        float sc = red[tid] + red[64 + tid] + red[128 + tid] + red[192 + tid];
        part[((size_t)nc * SEQ + s) * 64 + tid] = sc;
    }
}

// ---------------------------------------------------------------------------
// K4: softmax over s per batch.  (unchanged)
// ---------------------------------------------------------------------------
__global__ __launch_bounds__(512) void k4_softmax(
    const float* __restrict__ part, float* __restrict__ attn_out)
{
    const int b = blockIdx.x;
    const int t = threadIdx.x;
    __shared__ float red[8];
    __shared__ float smax, ssum;
    float myv = 0.f, val = -1e30f;
    if (t < SEQ) {
        myv = part[((size_t)0 * SEQ + t) * 64 + b]
            + part[((size_t)1 * SEQ + t) * 64 + b]
            + part[((size_t)2 * SEQ + t) * 64 + b]
            + part[((size_t)3 * SEQ + t) * 64 + b];
        val = myv;
    }
    float m = val;
    #pragma unroll
    for (int off = 32; off > 0; off >>= 1) m = fmaxf(m, __shfl_down(m, off, 64));
    if ((t & 63) == 0) red[t >> 6] = m;
    __syncthreads();
    if (t == 0) {
        float mm = red[0];
        #pragma unroll
        for (int w = 1; w < 8; ++w) mm = fmaxf(mm, red[w]);
        smax = mm;
    }
    __syncthreads();
    float e = (t < SEQ) ? expf(myv - smax) : 0.f;
    float ssv = e;
    #pragma unroll
    for (int off = 32; off > 0; off >>= 1) ssv += __shfl_down(ssv, off, 64);
    if ((t & 63) == 0) red[t >> 6] = ssv;
    __syncthreads();
    if (t == 0) {
        float ss = 0.f;
        #pragma unroll
        for (int w = 0; w < 8; ++w) ss += red[w];
        ssum = ss;
    }
    __syncthreads();
    if (t < SEQ) attn_out[t * 64 + b] = e / ssum;
}

// ---------------------------------------------------------------------------
// K5: context partials.  grid (64 b, 4 hc, 4 sg); 100 s each.  (unchanged)
// ---------------------------------------------------------------------------
__global__ __launch_bounds__(128) void k5_context(
    const float* __restrict__ enc, const float* __restrict__ attn,
    float* __restrict__ ctxp)
{
    const int b  = blockIdx.x;
    const int hc = blockIdx.y;
    const int sg = blockIdx.z;
    const int t  = threadIdx.x;
    __shared__ float a_s[100];
    if (t < 100) a_s[t] = attn[(sg * 100 + t) * 64 + b];
    __syncthreads();
    const int hh = hc * 128 + t;
    const float* p = enc + ((size_t)(sg * 100) * 64 + b) * H + hh;
    float a0 = 0.f, a1 = 0.f;
    #pragma unroll 5
    for (int i = 0; i < 100; i += 2) {
        a0 += a_s[i]     * p[0];
        a1 += a_s[i + 1] * p[(size_t)64 * H];
        p += (size_t)128 * H;
    }
    ctxp[((size_t)sg * 64 + b) * H + hh] = a0 + a1;
}

// ---------------------------------------------------------------------------
// K5b: reduce ctx partials; p[b] = sigmoid(ctx.pWh + h.pWs + x.pWx + b).
// ---------------------------------------------------------------------------
__global__ __launch_bounds__(512) void k5b_p(
    const float* __restrict__ ctxp, const float* __restrict__ pWh,
    const float* __restrict__ hdec, const float* __restrict__ pWs,
    const float* __restrict__ x, const float* __restrict__ pWx,
    const float* __restrict__ pWx_b,
    float* __restrict__ ctx, float* __restrict__ p_out, float* __restrict__ p_ws)
{
    const int b = blockIdx.x;
    const int t = threadIdx.x;
    __shared__ float rbuf[8];
    float c = ctxp[((size_t)0 * 64 + b) * H + t]
            + ctxp[((size_t)1 * 64 + b) * H + t]
            + ctxp[((size_t)2 * 64 + b) * H + t]
            + ctxp[((size_t)3 * 64 + b) * H + t];
    ctx[b * H + t] = c;
    float term = c * pWh[t] + hdec[b * H + t] * pWs[t] + x[b * H + t] * pWx[t];
    #pragma unroll
    for (int off = 32; off > 0; off >>= 1) term += __shfl_down(term, off, 64);
    if ((t & 63) == 0) rbuf[t >> 6] = term;
    __syncthreads();
    if (t == 0) {
        float ssv = pWx_b[0];
        #pragma unroll
        for (int w = 0; w < 8; ++w) ssv += rbuf[w];
        float pv = 1.f / (1.f + expf(-ssv));
        p_out[b] = pv;
        p_ws[b]  = pv;
    }
}

// ---------------------------------------------------------------------------
// K6 v5: MFMA, single-buffered, N=128 per block (grid 391) -- halves barrier
// count per out_W byte vs N=64 and doubles MFMA per staging barrier.
// HBM floor: out_W 205 MB ~= 33 us.
// ---------------------------------------------------------------------------
__global__ __launch_bounds__(256) void k6_vocab(
    const float* __restrict__ h, const float* __restrict__ ctx,
    const float* __restrict__ outW, const float* __restrict__ outb,
    const float* __restrict__ p_ws, float* __restrict__ ext)
{
    __shared__ uint4 AsG[512];    // 64 b  x 8 kg
    __shared__ uint4 BsG[1024];   // 128 v x 8 kg
    __shared__ float p_l[64];
    const int tid  = threadIdx.x;
    const int wave = tid >> 6, lane = tid & 63;
    const int lrow = lane & 15, q = lane >> 4;
    const int v0   = blockIdx.x * 128;

    if (tid < 64) p_l[tid] = p_ws[tid];

    floatx4 acc[4][2];
    #pragma unroll
    for (int mt = 0; mt < 4; ++mt)
        #pragma unroll
        for (int nt = 0; nt < 2; ++nt) acc[mt][nt] = (floatx4){0.f, 0.f, 0.f, 0.f};

    for (int kc = 0; kc < H2; kc += 64) {
        __syncthreads();
        const float* Ab = (kc < H) ? (h + kc) : (ctx + (kc - H));
        #pragma unroll
        for (int c = 0; c < 2; ++c) {           // gs tile
            int idx = c * 256 + tid;
            int m = idx >> 3, k8 = (idx & 7) ^ (m & 7);
            const float* sa = Ab + m * H + k8 * 8;
            AsG[idx] = pack8(ld4(sa), ld4(sa + 4));
        }
        #pragma unroll
        for (int c = 0; c < 4; ++c) {           // out_W tile (128 rows)
            int idx = c * 256 + tid;
            int n = idx >> 3, k8 = (idx & 7) ^ (n & 7);
            int vr = v0 + n; if (vr >= V) vr = V - 1;
            const float* sb = outW + (size_t)vr * H2 + kc + k8 * 8;
            BsG[idx] = pack8(ld4(sb), ld4(sb + 4));
        }
        __syncthreads();
        #pragma unroll
        for (int kk8 = 0; kk8 < 8; kk8 += 4) {
            const int k8 = kk8 + q;
            short8 a[4], b[2];
            #pragma unroll
            for (int mt = 0; mt < 4; ++mt) {
                int m = mt * 16 + lrow;
                a[mt] = *(const short8*)&AsG[m * 8 + (k8 ^ (m & 7))];
            }
            #pragma unroll
            for (int nt = 0; nt < 2; ++nt) {
                int n = wave * 32 + nt * 16 + lrow;
                b[nt] = *(const short8*)&BsG[n * 8 + (k8 ^ (n & 7))];
            }
            #pragma unroll
            for (int mt = 0; mt < 4; ++mt)
                #pragma unroll
                for (int nt = 0; nt < 2; ++nt)
                    acc[mt][nt] = __builtin_amdgcn_mfma_f32_16x16x32_bf16(
                        a[mt], b[nt], acc[mt][nt], 0, 0, 0);
        }
    }
    #pragma unroll
    for (int nt = 0; nt < 2; ++nt) {
        const int n = v0 + wave * 32 + nt * 16 + lrow;
        if (n < V) {
            const float ob = outb[n];
            #pragma unroll
            for (int mt = 0; mt < 4; ++mt) {
                #pragma unroll
                for (int r = 0; r < 4; ++r) {
                    const int bb = mt * 16 + q * 4 + r;
                    float zz = acc[mt][nt][r] + ob;
                    float sv = (zz > 0.f) ? 1.0507009873554805f * zz
                                          : 1.7580993408473766f * (expf(zz) - 1.f);
                    ext[(size_t)bb * EXT + n] = p_l[bb] * sv;
                }
            }
        }
    }
}

// ---------------------------------------------------------------------------
// K7: oov tail.  (unchanged)
// ---------------------------------------------------------------------------
__global__ __launch_bounds__(256) void k7_oov(
    const float* __restrict__ attn, const int* __restrict__ mask,
    const float* __restrict__ p_ws, float* __restrict__ ext)
{
    int e = blockIdx.x * 256 + threadIdx.x;
    if (e < SEQ * 64) {
        int s = e >> 6, b = e & 63;
        float val = (1.f - p_ws[b]) * attn[e] * (mask[e] ? 1.f : 0.f);
        ext[(size_t)b * EXT + V + s] = val;
    }
}

// ---------------------------------------------------------------------------
extern "C" void kernel_launch(void* const* d_in, const int* in_sizes, int n_in,
                              void* d_out, int out_size, void* d_ws, size_t ws_size,
                              hipStream_t stream)
{
    (void)in_sizes; (void)n_in; (void)out_size; (void)ws_size;
    const float* x      = (const float*)d_in[0];
    const float* enc    = (const float*)d_in[1];
    const int*   mask   = (const int*)  d_in[2];
    const float* h0     = (const float*)d_in[3];
    const float* W_ih   = (const float*)d_in[4];
    const float* W_hh   = (const float*)d_in[5];
    const float* b_ih   = (const float*)d_in[6];
    const float* b_hh   = (const float*)d_in[7];
    const float* outW   = (const float*)d_in[8];
    const float* outb   = (const float*)d_in[9];
    const float* v      = (const float*)d_in[10];
    const float* Wh     = (const float*)d_in[11];
    const float* Ws     = (const float*)d_in[12];
    const float* b_attn = (const float*)d_in[13];
    const float* pWh    = (const float*)d_in[14];
    const float* pWs    = (const float*)d_in[15];
    const float* pWx    = (const float*)d_in[16];
    const float* pWx_b  = (const float*)d_in[17];

    float* out        = (float*)d_out;
    float* out_ext    = out;                           // 64 x 50400
    float* out_hidden = out + (size_t)64 * EXT;        // 64 x 512
    float* out_p      = out_hidden + 64 * H;           // 64
    float* out_attn   = out_p + 64;                    // 400 x 64

    float* ws       = (float*)d_ws;
    float* ws_x2    = ws;                              // 64*512
    float* ws_part  = ws_x2 + 64 * H;                  // 4*400*64
    float* ws_ctxp  = ws_part + 4 * SEQ * 64;          // 4*64*512
    float* ws_ctx   = ws_ctxp + 4 * 64 * H;            // 64*512
    float* ws_p     = ws_ctx + 64 * H;                 // 64
    float* ws_gacc  = ws_p + 64;                       // 6*8*64*512 (6.3MB)
    unsigned short* ws_whT = (unsigned short*)(ws_gacc + 6 * 8 * 64 * H);
    unsigned short* ws_wsT = ws_whT + (size_t)H * H;

    k0_transpose<<<dim3(8, 8, 2), 256, 0, stream>>>(Wh, Ws, ws_whT, ws_wsT);
    k1_gru_part<<<dim3(8, 8), 256, 0, stream>>>(x, h0, W_ih, W_hh, ws_gacc);
    k1_gru_fin<<<128, 256, 0, stream>>>(ws_gacc, h0, b_ih, b_hh, out_hidden);
    k2_x2<<<8, 256, 0, stream>>>(out_hidden, ws_wsT, b_attn, ws_x2);
    k3_scores<<<dim3(SEQ, 4), 256, 0, stream>>>(enc, ws_whT, ws_x2, v, ws_part);
    k4_softmax<<<64, 512, 0, stream>>>(ws_part, out_attn);
    k5_context<<<dim3(64, 4, 4), 128, 0, stream>>>(enc, out_attn, ws_ctxp);
    k5b_p<<<64, 512, 0, stream>>>(ws_ctxp, pWh, out_hidden, pWs, x, pWx, pWx_b,
                                  ws_ctx, out_p, ws_p);
    k6_vocab<<<(V + 127) / 128, 256, 0, stream>>>(out_hidden, ws_ctx, outW, outb,
                                                  ws_p, out_ext);
    k7_oov<<<(SEQ * 64 + 255) / 256, 256, 0, stream>>>(out_attn, mask, ws_p, out_ext);
}